// Round 13
// baseline (503.871 us; speedup 1.0000x reference)
//
#include <hip/hip_runtime.h>

#define NN 50000
#define NE 800000
#define NG 64
#define BN_EPS 1e-5f

typedef unsigned short u16;
typedef unsigned int u32;
typedef unsigned char u8;
typedef long i64b;
struct alignas(8) us4 { u16 x, y, z, w; };
typedef float f32x4 __attribute__((ext_vector_type(4)));

__device__ inline int clampi(int v, int lo, int hi) {
  return v < lo ? lo : (v > hi ? hi : v);
}
// async global->LDS DMA, 16B per lane; LDS dest is wave-uniform base
__device__ inline void gload_lds16(const void* g, void* l) {
  __builtin_amdgcn_global_load_lds(
      (const __attribute__((address_space(1))) u32*)g,
      (__attribute__((address_space(3))) u32*)l, 16, 0, 0);
}
// fp8 e4m3 (OCP on gfx950) HW converts
__device__ inline float4 fp8x4f(u32 q) {
  float4 r;
  r.x = __builtin_amdgcn_cvt_f32_fp8(q, 0);
  r.y = __builtin_amdgcn_cvt_f32_fp8(q, 1);
  r.z = __builtin_amdgcn_cvt_f32_fp8(q, 2);
  r.w = __builtin_amdgcn_cvt_f32_fp8(q, 3);
  return r;
}
__device__ inline u32 f4fp8(float a, float b, float c, float d) {
  u32 p = __builtin_amdgcn_cvt_pk_fp8_f32(a, b, 0u, false);
  return __builtin_amdgcn_cvt_pk_fp8_f32(c, d, p, true);
}
__device__ inline u8 f2fp8(float v) {
  return (u8)(__builtin_amdgcn_cvt_pk_fp8_f32(v, 0.f, 0u, false) & 0xffu);
}

// ---------------- utility ----------------
__global__ void k_zero32(u32* __restrict__ p, int n) {
  int i = blockIdx.x * 256 + threadIdx.x;
  if (i < n) p[i] = 0u;
}

// fp32 [N*128] -> fp8 plane
__global__ void k_cvt_x(const float* __restrict__ x, u8* __restrict__ xf8) {
  int i = blockIdx.x * 256 + threadIdx.x;
  if (i >= NN * 128 / 8) return;
  size_t o = (size_t)i * 8;
  float4 a = *(const float4*)(x + o);
  float4 b = *(const float4*)(x + o + 4);
  u32 p0 = f4fp8(a.x, a.y, a.z, a.w);
  u32 p1 = f4fp8(b.x, b.y, b.z, b.w);
  *(uint2*)(xf8 + o) = make_uint2(p0, p1);
}

// ---------------- CSR build (proven) ----------------
__global__ void k_count(const int* __restrict__ dst, int* __restrict__ deg) {
  int e = blockIdx.x * 256 + threadIdx.x;
  if (e < NE) atomicAdd(&deg[clampi(dst[e], 0, NN - 1)], 1);
}

__global__ void k_scan_block(const int* __restrict__ deg, int* __restrict__ excl,
                             int* __restrict__ aux) {
  __shared__ int s[256];
  int t = threadIdx.x;
  int idx = blockIdx.x * 256 + t;
  int v = (idx < NN) ? deg[idx] : 0;
  s[t] = v;
  __syncthreads();
  for (int off = 1; off < 256; off <<= 1) {
    int x = (t >= off) ? s[t - off] : 0;
    __syncthreads();
    s[t] += x;
    __syncthreads();
  }
  if (idx < NN) excl[idx] = s[t] - v;
  if (t == 255) aux[blockIdx.x] = s[255];
}

__global__ void k_scan_aux(int* aux, int nblk) {
  __shared__ int s[256];
  int t = threadIdx.x;
  int v = (t < nblk) ? aux[t] : 0;
  s[t] = v;
  __syncthreads();
  for (int off = 1; off < 256; off <<= 1) {
    int x = (t >= off) ? s[t - off] : 0;
    __syncthreads();
    s[t] += x;
    __syncthreads();
  }
  if (t < nblk) aux[t] = s[t] - v;
}

__global__ void k_fix(int* __restrict__ rowptr, const int* __restrict__ aux,
                      int* __restrict__ cursor) {
  int idx = blockIdx.x * 256 + threadIdx.x;
  if (idx < NN) {
    int v = rowptr[idx] + aux[blockIdx.x];
    rowptr[idx] = v;
    cursor[idx] = v;
  }
  if (idx == 0) rowptr[NN] = NE;
}

__global__ void k_fill(const int* __restrict__ src, const int* __restrict__ dst,
                       const float* __restrict__ ew, int* __restrict__ cursor,
                       int* __restrict__ csr_src, float* __restrict__ csr_w) {
  int e = blockIdx.x * 256 + threadIdx.x;
  if (e < NE) {
    int d = clampi(dst[e], 0, NN - 1);
    int p = atomicAdd(&cursor[d], 1);
    p = clampi(p, 0, NE - 1);
    csr_src[p] = clampi(src[e], 0, NN - 1);
    csr_w[p] = ew[e];
  }
}

// --------- weight prep: Wt[n][k] = [Wl;Wr] concat along k (fp8) ---------
__global__ void k_wt(const float* __restrict__ Wl, const float* __restrict__ Wr,
                     int FIN, int FOUT, u8* __restrict__ t8) {
  int k = blockIdx.y * 256 + threadIdx.x;
  int n = blockIdx.x;
  int K = 2 * FIN;
  if (k >= K) return;
  float v = (k < FIN) ? Wl[(size_t)k * FOUT + n] : Wr[(size_t)(k - FIN) * FOUT + n];
  t8[(size_t)n * K + k] = f2fp8(v);
}

// --------- weight prep: Wt[n][k] = [Wl|Wr] concat along n (fp8) ---------
__global__ void k_wtn(const float* __restrict__ Wl, const float* __restrict__ Wr,
                      int Kdim, int half, u8* __restrict__ t8) {
  int k = blockIdx.y * 256 + threadIdx.x;
  int n = blockIdx.x;
  if (k >= Kdim) return;
  float v = (n < half) ? Wl[(size_t)k * half + n] : Wr[(size_t)k * half + (n - half)];
  t8[(size_t)n * Kdim + k] = f2fp8(v);
}

// ------- XCD-slice-blocked fp8 gathers: slice = bid & (NS-1) -------
// Table slice (NN x 64 fp8 = 3.2 MB) stays resident in one XCD's L2.
// Block: 256 thr = 16 nodes x 16 lanes; lane covers 4 cols of the slice.
__global__ void k_aggf512(const u8* __restrict__ xf8, const int* __restrict__ rowptr,
                          const int* __restrict__ csr_src, const float* __restrict__ csr_w,
                          u8* __restrict__ out) {
  int slice = blockIdx.x & 7;
  int node = (blockIdx.x >> 3) * 16 + (threadIdx.x >> 4);
  if (node >= NN) return;
  int cb = slice * 64 + (threadIdx.x & 15) * 4;
  int beg = rowptr[node], end = rowptr[node + 1];
  float4 acc = {0.f, 0.f, 0.f, 0.f};
  int e = beg;
  for (; e + 2 <= end; e += 2) {
    int s0 = csr_src[e], s1 = csr_src[e + 1];
    float w0 = csr_w[e], w1 = csr_w[e + 1];
    float4 v0 = fp8x4f(*(const u32*)(xf8 + (size_t)s0 * 512 + cb));
    float4 v1 = fp8x4f(*(const u32*)(xf8 + (size_t)s1 * 512 + cb));
    acc.x += v0.x * w0 + v1.x * w1;
    acc.y += v0.y * w0 + v1.y * w1;
    acc.z += v0.z * w0 + v1.z * w1;
    acc.w += v0.w * w0 + v1.w * w1;
  }
  if (e < end) {
    int s0 = csr_src[e];
    float w0 = csr_w[e];
    float4 v0 = fp8x4f(*(const u32*)(xf8 + (size_t)s0 * 512 + cb));
    acc.x += v0.x * w0; acc.y += v0.y * w0;
    acc.z += v0.z * w0; acc.w += v0.w * w0;
  }
  *(u32*)(out + (size_t)node * 512 + cb) = f4fp8(acc.x, acc.y, acc.z, acc.w);
}

__global__ void k_aggf128(const u8* __restrict__ xf8, const int* __restrict__ rowptr,
                          const int* __restrict__ csr_src, const float* __restrict__ csr_w,
                          u8* __restrict__ out) {
  int slice = blockIdx.x & 1;
  int node = (blockIdx.x >> 1) * 16 + (threadIdx.x >> 4);
  if (node >= NN) return;
  int cb = slice * 64 + (threadIdx.x & 15) * 4;
  int beg = rowptr[node], end = rowptr[node + 1];
  float4 acc = {0.f, 0.f, 0.f, 0.f};
  int e = beg;
  for (; e + 2 <= end; e += 2) {
    int s0 = csr_src[e], s1 = csr_src[e + 1];
    float w0 = csr_w[e], w1 = csr_w[e + 1];
    float4 v0 = fp8x4f(*(const u32*)(xf8 + (size_t)s0 * 128 + cb));
    float4 v1 = fp8x4f(*(const u32*)(xf8 + (size_t)s1 * 128 + cb));
    acc.x += v0.x * w0 + v1.x * w1;
    acc.y += v0.y * w0 + v1.y * w1;
    acc.z += v0.z * w0 + v1.z * w1;
    acc.w += v0.w * w0 + v1.w * w1;
  }
  if (e < end) {
    int s0 = csr_src[e];
    float w0 = csr_w[e];
    float4 v0 = fp8x4f(*(const u32*)(xf8 + (size_t)s0 * 128 + cb));
    acc.x += v0.x * w0; acc.y += v0.y * w0;
    acc.z += v0.z * w0; acc.w += v0.w * w0;
  }
  *(u32*)(out + (size_t)node * 128 + cb) = f4fp8(acc.x, acc.y, acc.z, acc.w);
}

// L3 combine: h3 = relu(agg256(P) + Q + bl3); PQ fp8 [N, P(256)|Q(256)]
__global__ void k_aggcomb(const u8* __restrict__ PQ, const int* __restrict__ rowptr,
                          const int* __restrict__ csr_src, const float* __restrict__ csr_w,
                          const float* __restrict__ bl3, float* __restrict__ h3) {
  int slice = blockIdx.x & 3;
  int node = (blockIdx.x >> 2) * 16 + (threadIdx.x >> 4);
  if (node >= NN) return;
  int cb = slice * 64 + (threadIdx.x & 15) * 4;
  int beg = rowptr[node], end = rowptr[node + 1];
  float4 acc = {0.f, 0.f, 0.f, 0.f};
  int e = beg;
  for (; e + 2 <= end; e += 2) {
    int s0 = csr_src[e], s1 = csr_src[e + 1];
    float w0 = csr_w[e], w1 = csr_w[e + 1];
    float4 v0 = fp8x4f(*(const u32*)(PQ + (size_t)s0 * 512 + cb));
    float4 v1 = fp8x4f(*(const u32*)(PQ + (size_t)s1 * 512 + cb));
    acc.x += v0.x * w0 + v1.x * w1;
    acc.y += v0.y * w0 + v1.y * w1;
    acc.z += v0.z * w0 + v1.z * w1;
    acc.w += v0.w * w0 + v1.w * w1;
  }
  if (e < end) {
    int s0 = csr_src[e];
    float w0 = csr_w[e];
    float4 v0 = fp8x4f(*(const u32*)(PQ + (size_t)s0 * 512 + cb));
    acc.x += v0.x * w0; acc.y += v0.y * w0;
    acc.z += v0.z * w0; acc.w += v0.w * w0;
  }
  float4 qv = fp8x4f(*(const u32*)(PQ + (size_t)node * 512 + 256 + cb));
  float4 bb = *(const float4*)(bl3 + cb);
  float4 o;
  o.x = fmaxf(acc.x + qv.x + bb.x, 0.f);
  o.y = fmaxf(acc.y + qv.y + bb.y, 0.f);
  o.z = fmaxf(acc.z + qv.z + bb.z, 0.f);
  o.w = fmaxf(acc.w + qv.w + bb.w, 0.f);
  *(float4*)(h3 + (size_t)node * 256 + cb) = o;
}

// ------- fp8 MFMA GEMM: O8[128x128 tiles] over A=[A0|A1], Wt[n][k] fp8 -------
// FOUT fixed 512. EPI: 0 = relu(v+bias); 1 = relu(BN(v+bias)); 2 = raw v.
// BK=128 fp8 (128B/row). global_load_lds w16, pre-swizzled src (16B-chunk XOR),
// XOR-swizzled ds_read_b64 frags, LDS-restaged coalesced fp8 output.
template <int K, int W0, int EPI>
__global__ __launch_bounds__(256) void k_gemm(
    const u8* __restrict__ A0, const u8* __restrict__ A1,
    const u8* __restrict__ Wt, const float* __restrict__ bias,
    const float* __restrict__ gamma, const float* __restrict__ beta,
    const float* __restrict__ mean, const float* __restrict__ var,
    u8* __restrict__ O8g) {
  constexpr int FOUT = 512;
  __shared__ char LDSC[32768];
  u8* AS = (u8*)LDSC;            // 16 KB A tile [128 rows][128 k fp8]
  u8* BS = (u8*)(LDSC + 16384);  // 16 KB B tile [128 cols][128 k fp8]
  int tid = threadIdx.x;
  int wid = tid >> 6, l = tid & 63;
  int wr = wid >> 1, wc = wid & 1;

  // bijective XCD swizzle + quad mapping
  int nwg = gridDim.x;  // 1564
  int q8 = nwg >> 3, r8 = nwg & 7;
  int xcd = blockIdx.x & 7, idx = blockIdx.x >> 3;
  int L = (xcd < r8 ? xcd * (q8 + 1) : r8 * (q8 + 1) + (xcd - r8) * q8) + idx;
  int n0 = (L >> 2) * 128, c0 = (L & 3) * 128;

  f32x4 acc[4][4] = {};

  int srw = 32 * wid + (l >> 3);  // staged row (+8j), 8 rows per instr
  int sch = l & 7;                // 16B chunk within 128B row

  for (int k0 = 0; k0 < K; k0 += 128) {
    __syncthreads();
    {
      const u8* s; int rs; int seg;
      if (k0 < W0) { s = A0; rs = W0; seg = k0; }
      else         { s = A1; rs = K - W0; seg = k0 - W0; }
#pragma unroll
      for (int j = 0; j < 4; ++j) {
        int r = srw + 8 * j;
        int gr = n0 + r;
        if (gr >= NN) gr = NN - 1;
        int cc = sch ^ (r & 7);
        gload_lds16(s + (size_t)gr * rs + seg + cc * 16, AS + (32 * wid + 8 * j) * 128);
      }
#pragma unroll
      for (int j = 0; j < 4; ++j) {
        int r = srw + 8 * j;
        int cc = sch ^ (r & 7);
        gload_lds16(Wt + (size_t)(c0 + r) * K + k0 + cc * 16, BS + (32 * wid + 8 * j) * 128);
      }
    }
    __syncthreads();

#pragma unroll
    for (int ks = 0; ks < 4; ++ks) {
      i64b b[4];
#pragma unroll
      for (int n = 0; n < 4; ++n) {
        int col = wc * 64 + n * 16 + (l & 15);
        int byte = (col * 128 + ks * 32 + ((l >> 4) << 3)) ^ ((col & 7) << 4);
        b[n] = *(const i64b*)((const char*)BS + byte);
      }
#pragma unroll
      for (int m = 0; m < 4; ++m) {
        int row = wr * 64 + m * 16 + (l & 15);
        int byte = (row * 128 + ks * 32 + ((l >> 4) << 3)) ^ ((row & 7) << 4);
        i64b a = *(const i64b*)((const char*)AS + byte);
#pragma unroll
        for (int n = 0; n < 4; ++n)
          acc[m][n] = __builtin_amdgcn_mfma_f32_16x16x32_fp8_fp8(a, b[n], acc[m][n], 0, 0, 0);
      }
    }
  }

  // ---- epilogue: EPI -> LDS restage (swizzled u8) -> coalesced 16B stores ----
  __syncthreads();
  u8* O8 = (u8*)LDSC;  // [128][128] u8 = 16 KB
#pragma unroll
  for (int n = 0; n < 4; ++n) {
    int colL = wc * 64 + n * 16 + (l & 15);
    int col = c0 + colL;
    float bs = (EPI == 2) ? 0.f : bias[col];
    float sc = 1.f, sf = 0.f;
    if (EPI == 1) {
      sc = rsqrtf(var[col] + BN_EPS) * gamma[col];
      sf = beta[col] - mean[col] * sc;
    }
#pragma unroll
    for (int m = 0; m < 4; ++m) {
      int rowL0 = wr * 64 + m * 16 + ((l >> 4) << 2);
#pragma unroll
      for (int r = 0; r < 4; ++r) {
        float v = acc[m][n][r];
        if (EPI != 2) {
          v += bs;
          if (EPI == 1) v = v * sc + sf;
          v = fmaxf(v, 0.f);
        }
        int rowL = rowL0 + r;
        int byte = (rowL * 128 + colL) ^ ((rowL & 7) << 4);
        O8[byte] = f2fp8(v);
      }
    }
  }
  __syncthreads();
#pragma unroll
  for (int i = 0; i < 4; ++i) {
    int chunk = i * 256 + tid;   // 0..1023 chunks of 16B
    int rowL = chunk >> 3;
    int cs = (chunk & 7) * 16;
    int rr = n0 + rowL;
    if (rr < NN) {
      int byte = (rowL * 128 + cs) ^ ((rowL & 7) << 4);
      *(uint4*)(O8g + (size_t)rr * FOUT + c0 + cs) = *(const uint4*)((const char*)O8 + byte);
    }
  }
}

// ---------------- pooling + MLP ----------------
__global__ void k_counts(const int* __restrict__ batch, float* __restrict__ cnt) {
  int g = threadIdx.x;  // 64 threads
  int lo = 0, hi = NN;
  while (lo < hi) { int m = (lo + hi) >> 1; if (batch[m] < g) lo = m + 1; else hi = m; }
  int a = lo;
  lo = 0; hi = NN;
  int g1 = g + 1;
  while (lo < hi) { int m = (lo + hi) >> 1; if (batch[m] < g1) lo = m + 1; else hi = m; }
  cnt[g] = (float)(lo - a);
}

__global__ void k_pool(const float* __restrict__ h, const int* __restrict__ batch,
                       float* __restrict__ sums) {
  int f = threadIdx.x;  // 256 features
  int n0 = blockIdx.x * 128;
  int n1 = n0 + 128; if (n1 > NN) n1 = NN;
  float acc = 0.f;
  int cur = clampi(batch[n0], 0, NG - 1);
  for (int n = n0; n < n1; ++n) {
    int g = clampi(batch[n], 0, NG - 1);
    if (g != cur) {
      atomicAdd(&sums[(size_t)cur * 256 + f], acc);
      acc = 0.f;
      cur = g;
    }
    acc += h[(size_t)n * 256 + f];
  }
  atomicAdd(&sums[(size_t)cur * 256 + f], acc);
}

__global__ void k_mlp(const float* __restrict__ sums, const float* __restrict__ cnt,
                      const float* __restrict__ W4, const float* __restrict__ b4,
                      const float* __restrict__ W5, const float* __restrict__ b5,
                      float* __restrict__ out) {
  __shared__ float g[256];
  int b = blockIdx.x, t = threadIdx.x;  // 64 threads
  float inv = 1.f / fmaxf(cnt[b], 1.f);
#pragma unroll
  for (int q = 0; q < 4; ++q) g[q * 64 + t] = sums[(size_t)b * 256 + q * 64 + t] * inv;
  __syncthreads();
  float acc = 0.f;
#pragma unroll 8
  for (int k = 0; k < 256; ++k) acc += g[k] * W4[k * 64 + t];
  float a = fmaxf(acc + b4[t], 0.f) * W5[t];
  for (int off = 32; off; off >>= 1) a += __shfl_down(a, off, 64);
  if (t == 0) out[b] = fmaxf(a + b5[0], 0.f);
}

// ---------------- launcher ----------------
extern "C" void kernel_launch(void* const* d_in, const int* in_sizes, int n_in,
                              void* d_out, int out_size, void* d_ws, size_t ws_size,
                              hipStream_t stream) {
  const float* x     = (const float*)d_in[0];
  const int*   eidx  = (const int*)d_in[1];
  const float* ew    = (const float*)d_in[2];
  const int*   batch = (const int*)d_in[3];
  const float* Wl1 = (const float*)d_in[4];
  const float* bl1 = (const float*)d_in[5];
  const float* Wr1 = (const float*)d_in[6];
  const float* Wl2 = (const float*)d_in[7];
  const float* bl2 = (const float*)d_in[8];
  const float* Wr2 = (const float*)d_in[9];
  const float* Wl3 = (const float*)d_in[10];
  const float* bl3 = (const float*)d_in[11];
  const float* Wr3 = (const float*)d_in[12];
  const float* gamma = (const float*)d_in[13];
  const float* beta  = (const float*)d_in[14];
  const float* mean  = (const float*)d_in[15];
  const float* var   = (const float*)d_in[16];
  const float* W4 = (const float*)d_in[17];
  const float* b4 = (const float*)d_in[18];
  const float* W5 = (const float*)d_in[19];
  const float* b5 = (const float*)d_in[20];

  const int* src = eidx;
  const int* dst = eidx + NE;

  // ---- workspace layout (~145 MB; ws_size known >= 313 MB) ----
  const size_t P8 = (size_t)NN * 512;      // 25.6 MB fp8 plane
  char* w = (char*)d_ws;
  u8*  X1f8 = (u8*)w; w += P8;             // h1 fp8
  u8*  X2f8 = (u8*)w; w += P8;             // h2 fp8
  u8*  Agf8 = (u8*)w; w += P8;             // agg stream; later PQ plane
  u8*  Xf8  = (u8*)w; w += (size_t)NN * 128;
  float* h3 = (float*)w; w += (size_t)NN * 256 * 4;  // 51.2 MB fp32
  u8* Wt1 = (u8*)w; w += (size_t)512 * 256;
  u8* Wt2 = (u8*)w; w += (size_t)512 * 1024;
  u8* Wt3 = (u8*)w; w += (size_t)512 * 512;
  int*   csr_src = (int*)w;   w += (size_t)NE * 4;
  float* csr_w   = (float*)w; w += (size_t)NE * 4;
  int*   rowptr  = (int*)w;   w += ((size_t)NN + 4) * 4;
  int*   cursor  = (int*)w;   w += (size_t)NN * 4;
  int*   aux     = (int*)w;   w += 1024;
  float* sums    = (float*)w; w += (size_t)NG * 256 * 4;
  float* cnt     = (float*)w; w += 1024;

  int nblk = (NN + 255) / 256;  // 196
  int ngrp = (NN + 15) / 16;    // 3125 (16 nodes per 256-thr block)

  // CSR build + input conversion + weight prep
  k_zero32<<<nblk, 256, 0, stream>>>((u32*)cursor, NN);
  k_count<<<(NE + 255) / 256, 256, 0, stream>>>(dst, cursor);
  k_scan_block<<<nblk, 256, 0, stream>>>(cursor, rowptr, aux);
  k_scan_aux<<<1, 256, 0, stream>>>(aux, nblk);
  k_fix<<<nblk, 256, 0, stream>>>(rowptr, aux, cursor);
  k_fill<<<(NE + 255) / 256, 256, 0, stream>>>(src, dst, ew, cursor, csr_src, csr_w);
  k_cvt_x<<<(NN * 128 / 8 + 255) / 256, 256, 0, stream>>>(x, Xf8);
  k_wt<<<dim3(512, 1), 256, 0, stream>>>(Wl1, Wr1, 128, 512, Wt1);
  k_wt<<<dim3(512, 4), 256, 0, stream>>>(Wl2, Wr2, 512, 512, Wt2);
  k_wtn<<<dim3(512, 2), 256, 0, stream>>>(Wl3, Wr3, 512, 256, Wt3);

  const int NWG = 391 * 4;  // 1564 (128x128 tiles over [50048 x 512])

  // Layer 1: agg(x fp8, 2 slices) -> Ag; h1 = relu([Ag|Xf8]@Wt1 + bl1) -> X1f8
  k_aggf128<<<ngrp * 2, 256, 0, stream>>>(Xf8, rowptr, csr_src, csr_w, Agf8);
  k_gemm<256, 128, 0><<<NWG, 256, 0, stream>>>(
      Agf8, Xf8, Wt1, bl1, nullptr, nullptr, nullptr, nullptr, X1f8);

  // Layer 2: agg(h1 fp8, 8 slices) -> Ag; h2 = relu(BN([Ag|h1]@Wt2 + bl2))
  k_aggf512<<<ngrp * 8, 256, 0, stream>>>(X1f8, rowptr, csr_src, csr_w, Agf8);
  k_gemm<1024, 512, 1><<<NWG, 256, 0, stream>>>(
      Agf8, X1f8, Wt2, bl2, gamma, beta, mean, var, X2f8);

  // Layer 3: PQ = h2 @ [Wl3|Wr3] -> Agf8 (raw); h3 = relu(agg(P, 4 slices) + Q + bl3)
  k_gemm<512, 512, 2><<<NWG, 256, 0, stream>>>(
      X2f8, X2f8, Wt3, nullptr, nullptr, nullptr, nullptr, nullptr, Agf8);
  k_aggcomb<<<ngrp * 4, 256, 0, stream>>>(Agf8, rowptr, csr_src, csr_w, bl3, h3);

  // pool + MLP
  k_zero32<<<(NG * 256 + 255) / 256, 256, 0, stream>>>((u32*)sums, NG * 256);
  k_pool<<<(NN + 127) / 128, 256, 0, stream>>>(h3, batch, sums);
  k_counts<<<1, 64, 0, stream>>>(batch, cnt);
  k_mlp<<<NG, 64, 0, stream>>>(sums, cnt, W4, b4, W5, b5, (float*)d_out);
}

// Round 14
// 467.320 us; speedup vs baseline: 1.0782x; 1.0782x over previous
//
#include <hip/hip_runtime.h>

#define NN 50000
#define NE 800000
#define NG 64
#define BN_EPS 1e-5f

typedef unsigned short u16;
typedef unsigned int u32;
typedef unsigned char u8;
typedef long i64b;
struct alignas(8) us4 { u16 x, y, z, w; };
typedef float f32x4 __attribute__((ext_vector_type(4)));

__device__ inline int clampi(int v, int lo, int hi) {
  return v < lo ? lo : (v > hi ? hi : v);
}
// async global->LDS DMA, 16B per lane; LDS dest is wave-uniform base
__device__ inline void gload_lds16(const void* g, void* l) {
  __builtin_amdgcn_global_load_lds(
      (const __attribute__((address_space(1))) u32*)g,
      (__attribute__((address_space(3))) u32*)l, 16, 0, 0);
}
// fp8 e4m3 (OCP on gfx950) HW converts
__device__ inline float4 fp8x4f(u32 q) {
  float4 r;
  r.x = __builtin_amdgcn_cvt_f32_fp8(q, 0);
  r.y = __builtin_amdgcn_cvt_f32_fp8(q, 1);
  r.z = __builtin_amdgcn_cvt_f32_fp8(q, 2);
  r.w = __builtin_amdgcn_cvt_f32_fp8(q, 3);
  return r;
}
__device__ inline u32 f4fp8(float a, float b, float c, float d) {
  u32 p = __builtin_amdgcn_cvt_pk_fp8_f32(a, b, 0u, false);
  return __builtin_amdgcn_cvt_pk_fp8_f32(c, d, p, true);
}
__device__ inline u8 f2fp8(float v) {
  return (u8)(__builtin_amdgcn_cvt_pk_fp8_f32(v, 0.f, 0u, false) & 0xffu);
}

// ---------------- utility ----------------
__global__ void k_zero32(u32* __restrict__ p, int n) {
  int i = blockIdx.x * 256 + threadIdx.x;
  if (i < n) p[i] = 0u;
}

// fp32 [N*128] -> fp8 plane
__global__ void k_cvt_x(const float* __restrict__ x, u8* __restrict__ xf8) {
  int i = blockIdx.x * 256 + threadIdx.x;
  if (i >= NN * 128 / 8) return;
  size_t o = (size_t)i * 8;
  float4 a = *(const float4*)(x + o);
  float4 b = *(const float4*)(x + o + 4);
  u32 p0 = f4fp8(a.x, a.y, a.z, a.w);
  u32 p1 = f4fp8(b.x, b.y, b.z, b.w);
  *(uint2*)(xf8 + o) = make_uint2(p0, p1);
}

// ---------------- CSR build (proven) ----------------
__global__ void k_count(const int* __restrict__ dst, int* __restrict__ deg) {
  int e = blockIdx.x * 256 + threadIdx.x;
  if (e < NE) atomicAdd(&deg[clampi(dst[e], 0, NN - 1)], 1);
}

__global__ void k_scan_block(const int* __restrict__ deg, int* __restrict__ excl,
                             int* __restrict__ aux) {
  __shared__ int s[256];
  int t = threadIdx.x;
  int idx = blockIdx.x * 256 + t;
  int v = (idx < NN) ? deg[idx] : 0;
  s[t] = v;
  __syncthreads();
  for (int off = 1; off < 256; off <<= 1) {
    int x = (t >= off) ? s[t - off] : 0;
    __syncthreads();
    s[t] += x;
    __syncthreads();
  }
  if (idx < NN) excl[idx] = s[t] - v;
  if (t == 255) aux[blockIdx.x] = s[255];
}

__global__ void k_scan_aux(int* aux, int nblk) {
  __shared__ int s[256];
  int t = threadIdx.x;
  int v = (t < nblk) ? aux[t] : 0;
  s[t] = v;
  __syncthreads();
  for (int off = 1; off < 256; off <<= 1) {
    int x = (t >= off) ? s[t - off] : 0;
    __syncthreads();
    s[t] += x;
    __syncthreads();
  }
  if (t < nblk) aux[t] = s[t] - v;
}

__global__ void k_fix(int* __restrict__ rowptr, const int* __restrict__ aux,
                      int* __restrict__ cursor) {
  int idx = blockIdx.x * 256 + threadIdx.x;
  if (idx < NN) {
    int v = rowptr[idx] + aux[blockIdx.x];
    rowptr[idx] = v;
    cursor[idx] = v;
  }
  if (idx == 0) rowptr[NN] = NE;
}

__global__ void k_fill(const int* __restrict__ src, const int* __restrict__ dst,
                       const float* __restrict__ ew, int* __restrict__ cursor,
                       int* __restrict__ csr_src, float* __restrict__ csr_w) {
  int e = blockIdx.x * 256 + threadIdx.x;
  if (e < NE) {
    int d = clampi(dst[e], 0, NN - 1);
    int p = atomicAdd(&cursor[d], 1);
    p = clampi(p, 0, NE - 1);
    csr_src[p] = clampi(src[e], 0, NN - 1);
    csr_w[p] = ew[e];
  }
}

// --------- weight prep: Wt[n][k] = [Wl;Wr] concat along k (fp8) ---------
__global__ void k_wt(const float* __restrict__ Wl, const float* __restrict__ Wr,
                     int FIN, int FOUT, u8* __restrict__ t8) {
  int k = blockIdx.y * 256 + threadIdx.x;
  int n = blockIdx.x;
  int K = 2 * FIN;
  if (k >= K) return;
  float v = (k < FIN) ? Wl[(size_t)k * FOUT + n] : Wr[(size_t)(k - FIN) * FOUT + n];
  t8[(size_t)n * K + k] = f2fp8(v);
}

// --------- weight prep: Wt[n][k] = [Wl|Wr] concat along n (fp8) ---------
__global__ void k_wtn(const float* __restrict__ Wl, const float* __restrict__ Wr,
                      int Kdim, int half, u8* __restrict__ t8) {
  int k = blockIdx.y * 256 + threadIdx.x;
  int n = blockIdx.x;
  if (k >= Kdim) return;
  float v = (n < half) ? Wl[(size_t)k * half + n] : Wr[(size_t)k * half + (n - half)];
  t8[(size_t)n * Kdim + k] = f2fp8(v);
}

// ---------------- aggregation (fp8 gather over CSR, fp8 out) ----------------
// R12 structure (proven 66us) + x4 unroll + nontemporal CSR/output.
__global__ void k_aggf512(const u8* __restrict__ xf8, const int* __restrict__ rowptr,
                          const int* __restrict__ csr_src, const float* __restrict__ csr_w,
                          u8* __restrict__ out) {
  int n = blockIdx.x;
  int t = threadIdx.x;  // 0..127
  int beg = rowptr[n], end = rowptr[n + 1];
  float4 acc = {0.f, 0.f, 0.f, 0.f};
  int e = beg;
  for (; e + 4 <= end; e += 4) {
    int s0 = __builtin_nontemporal_load(csr_src + e);
    int s1 = __builtin_nontemporal_load(csr_src + e + 1);
    int s2 = __builtin_nontemporal_load(csr_src + e + 2);
    int s3 = __builtin_nontemporal_load(csr_src + e + 3);
    float w0 = __builtin_nontemporal_load(csr_w + e);
    float w1 = __builtin_nontemporal_load(csr_w + e + 1);
    float w2 = __builtin_nontemporal_load(csr_w + e + 2);
    float w3 = __builtin_nontemporal_load(csr_w + e + 3);
    u32 q0 = *(const u32*)(xf8 + (size_t)s0 * 512 + t * 4);
    u32 q1 = *(const u32*)(xf8 + (size_t)s1 * 512 + t * 4);
    u32 q2 = *(const u32*)(xf8 + (size_t)s2 * 512 + t * 4);
    u32 q3 = *(const u32*)(xf8 + (size_t)s3 * 512 + t * 4);
    float4 v0 = fp8x4f(q0), v1 = fp8x4f(q1), v2 = fp8x4f(q2), v3 = fp8x4f(q3);
    acc.x += v0.x * w0 + v1.x * w1 + v2.x * w2 + v3.x * w3;
    acc.y += v0.y * w0 + v1.y * w1 + v2.y * w2 + v3.y * w3;
    acc.z += v0.z * w0 + v1.z * w1 + v2.z * w2 + v3.z * w3;
    acc.w += v0.w * w0 + v1.w * w1 + v2.w * w2 + v3.w * w3;
  }
  for (; e < end; ++e) {
    int s0 = __builtin_nontemporal_load(csr_src + e);
    float w0 = __builtin_nontemporal_load(csr_w + e);
    float4 v0 = fp8x4f(*(const u32*)(xf8 + (size_t)s0 * 512 + t * 4));
    acc.x += v0.x * w0; acc.y += v0.y * w0;
    acc.z += v0.z * w0; acc.w += v0.w * w0;
  }
  __builtin_nontemporal_store(f4fp8(acc.x, acc.y, acc.z, acc.w),
                              (u32*)(out + (size_t)n * 512 + t * 4));
}

__global__ void k_aggf128(const u8* __restrict__ xf8, const int* __restrict__ rowptr,
                          const int* __restrict__ csr_src, const float* __restrict__ csr_w,
                          u8* __restrict__ out) {
  int sub = threadIdx.x >> 5;
  int lane = threadIdx.x & 31;
  int n = blockIdx.x * 2 + sub;
  if (n >= NN) return;
  int beg = rowptr[n], end = rowptr[n + 1];
  float4 acc = {0.f, 0.f, 0.f, 0.f};
  int e = beg;
  for (; e + 2 <= end; e += 2) {
    int s0 = __builtin_nontemporal_load(csr_src + e);
    int s1 = __builtin_nontemporal_load(csr_src + e + 1);
    float w0 = __builtin_nontemporal_load(csr_w + e);
    float w1 = __builtin_nontemporal_load(csr_w + e + 1);
    float4 v0 = fp8x4f(*(const u32*)(xf8 + (size_t)s0 * 128 + lane * 4));
    float4 v1 = fp8x4f(*(const u32*)(xf8 + (size_t)s1 * 128 + lane * 4));
    acc.x += v0.x * w0 + v1.x * w1;
    acc.y += v0.y * w0 + v1.y * w1;
    acc.z += v0.z * w0 + v1.z * w1;
    acc.w += v0.w * w0 + v1.w * w1;
  }
  if (e < end) {
    int s0 = __builtin_nontemporal_load(csr_src + e);
    float w0 = __builtin_nontemporal_load(csr_w + e);
    float4 v0 = fp8x4f(*(const u32*)(xf8 + (size_t)s0 * 128 + lane * 4));
    acc.x += v0.x * w0; acc.y += v0.y * w0;
    acc.z += v0.z * w0; acc.w += v0.w * w0;
  }
  __builtin_nontemporal_store(f4fp8(acc.x, acc.y, acc.z, acc.w),
                              (u32*)(out + (size_t)n * 128 + lane * 4));
}

// L3 combine: h3 = relu(agg256(P) + Q + bl3); PQ fp8 [N, P(256)|Q(256)]
__global__ void k_aggcomb(const u8* __restrict__ PQ, const int* __restrict__ rowptr,
                          const int* __restrict__ csr_src, const float* __restrict__ csr_w,
                          const float* __restrict__ bl3, float* __restrict__ h3) {
  int sub = threadIdx.x >> 6;
  int lane = threadIdx.x & 63;
  int n = blockIdx.x * 2 + sub;
  if (n >= NN) return;
  int beg = rowptr[n], end = rowptr[n + 1];
  float4 acc = {0.f, 0.f, 0.f, 0.f};
  int e = beg;
  for (; e + 2 <= end; e += 2) {
    int s0 = __builtin_nontemporal_load(csr_src + e);
    int s1 = __builtin_nontemporal_load(csr_src + e + 1);
    float w0 = __builtin_nontemporal_load(csr_w + e);
    float w1 = __builtin_nontemporal_load(csr_w + e + 1);
    float4 v0 = fp8x4f(*(const u32*)(PQ + (size_t)s0 * 512 + lane * 4));
    float4 v1 = fp8x4f(*(const u32*)(PQ + (size_t)s1 * 512 + lane * 4));
    acc.x += v0.x * w0 + v1.x * w1;
    acc.y += v0.y * w0 + v1.y * w1;
    acc.z += v0.z * w0 + v1.z * w1;
    acc.w += v0.w * w0 + v1.w * w1;
  }
  if (e < end) {
    int s0 = __builtin_nontemporal_load(csr_src + e);
    float w0 = __builtin_nontemporal_load(csr_w + e);
    float4 v0 = fp8x4f(*(const u32*)(PQ + (size_t)s0 * 512 + lane * 4));
    acc.x += v0.x * w0; acc.y += v0.y * w0;
    acc.z += v0.z * w0; acc.w += v0.w * w0;
  }
  float4 qv = fp8x4f(*(const u32*)(PQ + (size_t)n * 512 + 256 + lane * 4));
  float4 bb = *(const float4*)(bl3 + lane * 4);
  float4 o;
  o.x = fmaxf(acc.x + qv.x + bb.x, 0.f);
  o.y = fmaxf(acc.y + qv.y + bb.y, 0.f);
  o.z = fmaxf(acc.z + qv.z + bb.z, 0.f);
  o.w = fmaxf(acc.w + qv.w + bb.w, 0.f);
  *(float4*)(h3 + (size_t)n * 256 + lane * 4) = o;
}

// ------- fp8 MFMA GEMM: O8[128x128 tiles] over A=[A0|A1], Wt[n][k] fp8 -------
// FOUT fixed 512. EPI: 0 = relu(v+bias); 1 = relu(BN(v+bias)); 2 = raw v.
// BK=128 fp8 (128B/row). global_load_lds w16, pre-swizzled src (16B-chunk XOR),
// XOR-swizzled ds_read_b64 frags, LDS-restaged coalesced fp8 output.
template <int K, int W0, int EPI>
__global__ __launch_bounds__(256) void k_gemm(
    const u8* __restrict__ A0, const u8* __restrict__ A1,
    const u8* __restrict__ Wt, const float* __restrict__ bias,
    const float* __restrict__ gamma, const float* __restrict__ beta,
    const float* __restrict__ mean, const float* __restrict__ var,
    u8* __restrict__ O8g) {
  constexpr int FOUT = 512;
  __shared__ char LDSC[32768];
  u8* AS = (u8*)LDSC;            // 16 KB A tile [128 rows][128 k fp8]
  u8* BS = (u8*)(LDSC + 16384);  // 16 KB B tile [128 cols][128 k fp8]
  int tid = threadIdx.x;
  int wid = tid >> 6, l = tid & 63;
  int wr = wid >> 1, wc = wid & 1;

  // bijective XCD swizzle + quad mapping
  int nwg = gridDim.x;  // 1564
  int q8 = nwg >> 3, r8 = nwg & 7;
  int xcd = blockIdx.x & 7, idx = blockIdx.x >> 3;
  int L = (xcd < r8 ? xcd * (q8 + 1) : r8 * (q8 + 1) + (xcd - r8) * q8) + idx;
  int n0 = (L >> 2) * 128, c0 = (L & 3) * 128;

  f32x4 acc[4][4] = {};

  int srw = 32 * wid + (l >> 3);  // staged row (+8j), 8 rows per instr
  int sch = l & 7;                // 16B chunk within 128B row

  for (int k0 = 0; k0 < K; k0 += 128) {
    __syncthreads();
    {
      const u8* s; int rs; int seg;
      if (k0 < W0) { s = A0; rs = W0; seg = k0; }
      else         { s = A1; rs = K - W0; seg = k0 - W0; }
#pragma unroll
      for (int j = 0; j < 4; ++j) {
        int r = srw + 8 * j;
        int gr = n0 + r;
        if (gr >= NN) gr = NN - 1;
        int cc = sch ^ (r & 7);
        gload_lds16(s + (size_t)gr * rs + seg + cc * 16, AS + (32 * wid + 8 * j) * 128);
      }
#pragma unroll
      for (int j = 0; j < 4; ++j) {
        int r = srw + 8 * j;
        int cc = sch ^ (r & 7);
        gload_lds16(Wt + (size_t)(c0 + r) * K + k0 + cc * 16, BS + (32 * wid + 8 * j) * 128);
      }
    }
    __syncthreads();

#pragma unroll
    for (int ks = 0; ks < 4; ++ks) {
      i64b b[4];
#pragma unroll
      for (int n = 0; n < 4; ++n) {
        int col = wc * 64 + n * 16 + (l & 15);
        int byte = (col * 128 + ks * 32 + ((l >> 4) << 3)) ^ ((col & 7) << 4);
        b[n] = *(const i64b*)((const char*)BS + byte);
      }
#pragma unroll
      for (int m = 0; m < 4; ++m) {
        int row = wr * 64 + m * 16 + (l & 15);
        int byte = (row * 128 + ks * 32 + ((l >> 4) << 3)) ^ ((row & 7) << 4);
        i64b a = *(const i64b*)((const char*)AS + byte);
#pragma unroll
        for (int n = 0; n < 4; ++n)
          acc[m][n] = __builtin_amdgcn_mfma_f32_16x16x32_fp8_fp8(a, b[n], acc[m][n], 0, 0, 0);
      }
    }
  }

  // ---- epilogue: EPI -> LDS restage (swizzled u8) -> coalesced 16B stores ----
  __syncthreads();
  u8* O8 = (u8*)LDSC;  // [128][128] u8 = 16 KB
#pragma unroll
  for (int n = 0; n < 4; ++n) {
    int colL = wc * 64 + n * 16 + (l & 15);
    int col = c0 + colL;
    float bs = (EPI == 2) ? 0.f : bias[col];
    float sc = 1.f, sf = 0.f;
    if (EPI == 1) {
      sc = rsqrtf(var[col] + BN_EPS) * gamma[col];
      sf = beta[col] - mean[col] * sc;
    }
#pragma unroll
    for (int m = 0; m < 4; ++m) {
      int rowL0 = wr * 64 + m * 16 + ((l >> 4) << 2);
#pragma unroll
      for (int r = 0; r < 4; ++r) {
        float v = acc[m][n][r];
        if (EPI != 2) {
          v += bs;
          if (EPI == 1) v = v * sc + sf;
          v = fmaxf(v, 0.f);
        }
        int rowL = rowL0 + r;
        int byte = (rowL * 128 + colL) ^ ((rowL & 7) << 4);
        O8[byte] = f2fp8(v);
      }
    }
  }
  __syncthreads();
#pragma unroll
  for (int i = 0; i < 4; ++i) {
    int chunk = i * 256 + tid;   // 0..1023 chunks of 16B
    int rowL = chunk >> 3;
    int cs = (chunk & 7) * 16;
    int rr = n0 + rowL;
    if (rr < NN) {
      int byte = (rowL * 128 + cs) ^ ((rowL & 7) << 4);
      *(uint4*)(O8g + (size_t)rr * FOUT + c0 + cs) = *(const uint4*)((const char*)O8 + byte);
    }
  }
}

// ---------------- pooling + MLP ----------------
__global__ void k_counts(const int* __restrict__ batch, float* __restrict__ cnt) {
  int g = threadIdx.x;  // 64 threads
  int lo = 0, hi = NN;
  while (lo < hi) { int m = (lo + hi) >> 1; if (batch[m] < g) lo = m + 1; else hi = m; }
  int a = lo;
  lo = 0; hi = NN;
  int g1 = g + 1;
  while (lo < hi) { int m = (lo + hi) >> 1; if (batch[m] < g1) lo = m + 1; else hi = m; }
  cnt[g] = (float)(lo - a);
}

__global__ void k_pool(const float* __restrict__ h, const int* __restrict__ batch,
                       float* __restrict__ sums) {
  int f = threadIdx.x;  // 256 features
  int n0 = blockIdx.x * 128;
  int n1 = n0 + 128; if (n1 > NN) n1 = NN;
  float acc = 0.f;
  int cur = clampi(batch[n0], 0, NG - 1);
  for (int n = n0; n < n1; ++n) {
    int g = clampi(batch[n], 0, NG - 1);
    if (g != cur) {
      atomicAdd(&sums[(size_t)cur * 256 + f], acc);
      acc = 0.f;
      cur = g;
    }
    acc += h[(size_t)n * 256 + f];
  }
  atomicAdd(&sums[(size_t)cur * 256 + f], acc);
}

__global__ void k_mlp(const float* __restrict__ sums, const float* __restrict__ cnt,
                      const float* __restrict__ W4, const float* __restrict__ b4,
                      const float* __restrict__ W5, const float* __restrict__ b5,
                      float* __restrict__ out) {
  __shared__ float g[256];
  int b = blockIdx.x, t = threadIdx.x;  // 64 threads
  float inv = 1.f / fmaxf(cnt[b], 1.f);
#pragma unroll
  for (int q = 0; q < 4; ++q) g[q * 64 + t] = sums[(size_t)b * 256 + q * 64 + t] * inv;
  __syncthreads();
  float acc = 0.f;
#pragma unroll 8
  for (int k = 0; k < 256; ++k) acc += g[k] * W4[k * 64 + t];
  float a = fmaxf(acc + b4[t], 0.f) * W5[t];
  for (int off = 32; off; off >>= 1) a += __shfl_down(a, off, 64);
  if (t == 0) out[b] = fmaxf(a + b5[0], 0.f);
}

// ---------------- launcher ----------------
extern "C" void kernel_launch(void* const* d_in, const int* in_sizes, int n_in,
                              void* d_out, int out_size, void* d_ws, size_t ws_size,
                              hipStream_t stream) {
  const float* x     = (const float*)d_in[0];
  const int*   eidx  = (const int*)d_in[1];
  const float* ew    = (const float*)d_in[2];
  const int*   batch = (const int*)d_in[3];
  const float* Wl1 = (const float*)d_in[4];
  const float* bl1 = (const float*)d_in[5];
  const float* Wr1 = (const float*)d_in[6];
  const float* Wl2 = (const float*)d_in[7];
  const float* bl2 = (const float*)d_in[8];
  const float* Wr2 = (const float*)d_in[9];
  const float* Wl3 = (const float*)d_in[10];
  const float* bl3 = (const float*)d_in[11];
  const float* Wr3 = (const float*)d_in[12];
  const float* gamma = (const float*)d_in[13];
  const float* beta  = (const float*)d_in[14];
  const float* mean  = (const float*)d_in[15];
  const float* var   = (const float*)d_in[16];
  const float* W4 = (const float*)d_in[17];
  const float* b4 = (const float*)d_in[18];
  const float* W5 = (const float*)d_in[19];
  const float* b5 = (const float*)d_in[20];

  const int* src = eidx;
  const int* dst = eidx + NE;

  // ---- workspace layout (~145 MB; ws_size known >= 313 MB) ----
  const size_t P8 = (size_t)NN * 512;      // 25.6 MB fp8 plane
  char* w = (char*)d_ws;
  u8*  X1f8 = (u8*)w; w += P8;             // h1 fp8
  u8*  X2f8 = (u8*)w; w += P8;             // h2 fp8
  u8*  Agf8 = (u8*)w; w += P8;             // agg stream; later PQ plane
  u8*  Xf8  = (u8*)w; w += (size_t)NN * 128;
  float* h3 = (float*)w; w += (size_t)NN * 256 * 4;  // 51.2 MB fp32
  u8* Wt1 = (u8*)w; w += (size_t)512 * 256;
  u8* Wt2 = (u8*)w; w += (size_t)512 * 1024;
  u8* Wt3 = (u8*)w; w += (size_t)512 * 512;
  int*   csr_src = (int*)w;   w += (size_t)NE * 4;
  float* csr_w   = (float*)w; w += (size_t)NE * 4;
  int*   rowptr  = (int*)w;   w += ((size_t)NN + 4) * 4;
  int*   cursor  = (int*)w;   w += (size_t)NN * 4;
  int*   aux     = (int*)w;   w += 1024;
  float* sums    = (float*)w; w += (size_t)NG * 256 * 4;
  float* cnt     = (float*)w; w += 1024;

  int nblk = (NN + 255) / 256;  // 196

  // CSR build + input conversion + weight prep
  k_zero32<<<nblk, 256, 0, stream>>>((u32*)cursor, NN);
  k_count<<<(NE + 255) / 256, 256, 0, stream>>>(dst, cursor);
  k_scan_block<<<nblk, 256, 0, stream>>>(cursor, rowptr, aux);
  k_scan_aux<<<1, 256, 0, stream>>>(aux, nblk);
  k_fix<<<nblk, 256, 0, stream>>>(rowptr, aux, cursor);
  k_fill<<<(NE + 255) / 256, 256, 0, stream>>>(src, dst, ew, cursor, csr_src, csr_w);
  k_cvt_x<<<(NN * 128 / 8 + 255) / 256, 256, 0, stream>>>(x, Xf8);
  k_wt<<<dim3(512, 1), 256, 0, stream>>>(Wl1, Wr1, 128, 512, Wt1);
  k_wt<<<dim3(512, 4), 256, 0, stream>>>(Wl2, Wr2, 512, 512, Wt2);
  k_wtn<<<dim3(512, 2), 256, 0, stream>>>(Wl3, Wr3, 512, 256, Wt3);

  const int NWG = 391 * 4;  // 1564 (128x128 tiles over [50048 x 512])

  // Layer 1: agg(x fp8) -> Ag; h1 = relu([Ag|Xf8]@Wt1 + bl1) -> X1f8
  k_aggf128<<<(NN + 1) / 2, 64, 0, stream>>>(Xf8, rowptr, csr_src, csr_w, Agf8);
  k_gemm<256, 128, 0><<<NWG, 256, 0, stream>>>(
      Agf8, Xf8, Wt1, bl1, nullptr, nullptr, nullptr, nullptr, X1f8);

  // Layer 2: agg(h1 fp8) -> Ag; h2 = relu(BN([Ag|h1]@Wt2 + bl2)) -> X2f8
  k_aggf512<<<NN, 128, 0, stream>>>(X1f8, rowptr, csr_src, csr_w, Agf8);
  k_gemm<1024, 512, 1><<<NWG, 256, 0, stream>>>(
      Agf8, X1f8, Wt2, bl2, gamma, beta, mean, var, X2f8);

  // Layer 3: PQ = h2 @ [Wl3|Wr3] -> Agf8 (raw); h3 = relu(agg(P) + Q + bl3)
  k_gemm<512, 512, 2><<<NWG, 256, 0, stream>>>(
      X2f8, X2f8, Wt3, nullptr, nullptr, nullptr, nullptr, nullptr, Agf8);
  k_aggcomb<<<(NN + 1) / 2, 128, 0, stream>>>(Agf8, rowptr, csr_src, csr_w, bl3, h3);

  // pool + MLP
  k_zero32<<<(NG * 256 + 255) / 256, 256, 0, stream>>>((u32*)sums, NG * 256);
  k_pool<<<(NN + 127) / 128, 256, 0, stream>>>(h3, batch, sums);
  k_counts<<<1, 64, 0, stream>>>(batch, cnt);
  k_mlp<<<NG, 64, 0, stream>>>(sums, cnt, W4, b4, W5, b5, (float*)d_out);
}

// Round 15
// 427.831 us; speedup vs baseline: 1.1777x; 1.0923x over previous
//
#include <hip/hip_runtime.h>

#define NN 50000
#define NE 800000
#define NG 64
#define BN_EPS 1e-5f

typedef unsigned short u16;
typedef unsigned int u32;
typedef unsigned char u8;
typedef long i64b;
struct alignas(8) us4 { u16 x, y, z, w; };
typedef float f32x4 __attribute__((ext_vector_type(4)));

__device__ inline int clampi(int v, int lo, int hi) {
  return v < lo ? lo : (v > hi ? hi : v);
}
// async global->LDS DMA, 16B per lane; LDS dest is wave-uniform base
__device__ inline void gload_lds16(const void* g, void* l) {
  __builtin_amdgcn_global_load_lds(
      (const __attribute__((address_space(1))) u32*)g,
      (__attribute__((address_space(3))) u32*)l, 16, 0, 0);
}
// fp8 e4m3 (OCP on gfx950) HW converts
__device__ inline float4 fp8x4f(u32 q) {
  float4 r;
  r.x = __builtin_amdgcn_cvt_f32_fp8(q, 0);
  r.y = __builtin_amdgcn_cvt_f32_fp8(q, 1);
  r.z = __builtin_amdgcn_cvt_f32_fp8(q, 2);
  r.w = __builtin_amdgcn_cvt_f32_fp8(q, 3);
  return r;
}
__device__ inline u32 f4fp8(float a, float b, float c, float d) {
  u32 p = __builtin_amdgcn_cvt_pk_fp8_f32(a, b, 0u, false);
  return __builtin_amdgcn_cvt_pk_fp8_f32(c, d, p, true);
}
__device__ inline u8 f2fp8(float v) {
  return (u8)(__builtin_amdgcn_cvt_pk_fp8_f32(v, 0.f, 0u, false) & 0xffu);
}

// ---------------- utility ----------------
__global__ void k_zero32(u32* __restrict__ p, int n) {
  int i = blockIdx.x * 256 + threadIdx.x;
  if (i < n) p[i] = 0u;
}

// ---------------- CSR build (proven) ----------------
__global__ void k_count(const int* __restrict__ dst, int* __restrict__ deg) {
  int e = blockIdx.x * 256 + threadIdx.x;
  if (e < NE) atomicAdd(&deg[clampi(dst[e], 0, NN - 1)], 1);
}

__global__ void k_scan_block(const int* __restrict__ deg, int* __restrict__ excl,
                             int* __restrict__ aux) {
  __shared__ int s[256];
  int t = threadIdx.x;
  int idx = blockIdx.x * 256 + t;
  int v = (idx < NN) ? deg[idx] : 0;
  s[t] = v;
  __syncthreads();
  for (int off = 1; off < 256; off <<= 1) {
    int x = (t >= off) ? s[t - off] : 0;
    __syncthreads();
    s[t] += x;
    __syncthreads();
  }
  if (idx < NN) excl[idx] = s[t] - v;
  if (t == 255) aux[blockIdx.x] = s[255];
}

__global__ void k_scan_aux(int* aux, int nblk) {
  __shared__ int s[256];
  int t = threadIdx.x;
  int v = (t < nblk) ? aux[t] : 0;
  s[t] = v;
  __syncthreads();
  for (int off = 1; off < 256; off <<= 1) {
    int x = (t >= off) ? s[t - off] : 0;
    __syncthreads();
    s[t] += x;
    __syncthreads();
  }
  if (t < nblk) aux[t] = s[t] - v;
}

__global__ void k_fix(int* __restrict__ rowptr, const int* __restrict__ aux,
                      int* __restrict__ cursor) {
  int idx = blockIdx.x * 256 + threadIdx.x;
  if (idx < NN) {
    int v = rowptr[idx] + aux[blockIdx.x];
    rowptr[idx] = v;
    cursor[idx] = v;
  }
  if (idx == 0) rowptr[NN] = NE;
}

__global__ void k_fill(const int* __restrict__ src, const int* __restrict__ dst,
                       const float* __restrict__ ew, int* __restrict__ cursor,
                       int* __restrict__ csr_src, float* __restrict__ csr_w) {
  int e = blockIdx.x * 256 + threadIdx.x;
  if (e < NE) {
    int d = clampi(dst[e], 0, NN - 1);
    int p = atomicAdd(&cursor[d], 1);
    p = clampi(p, 0, NE - 1);
    csr_src[p] = clampi(src[e], 0, NN - 1);
    csr_w[p] = ew[e];
  }
}

// ------- fused prep: weight transposes (fp8) + x -> fp8 conversion -------
// b<512: Wt1[n=b][k<256]; b<1024: Wt2[n][k<1024]; b<1536: Wt3[n][k<512];
// b>=1536: cvt_x chunk.
__global__ void k_prep(const float* __restrict__ x, u8* __restrict__ xf8,
                       const float* __restrict__ Wl1, const float* __restrict__ Wr1,
                       u8* __restrict__ t1,
                       const float* __restrict__ Wl2, const float* __restrict__ Wr2,
                       u8* __restrict__ t2,
                       const float* __restrict__ Wl3, const float* __restrict__ Wr3,
                       u8* __restrict__ t3) {
  int b = blockIdx.x, tid = threadIdx.x;
  if (b < 512) {
    int n = b, k = tid;  // K=256, FIN=128, FOUT=512
    float v = (k < 128) ? Wl1[(size_t)k * 512 + n] : Wr1[(size_t)(k - 128) * 512 + n];
    t1[(size_t)n * 256 + k] = f2fp8(v);
  } else if (b < 1024) {
    int n = b - 512;     // K=1024, FIN=512, FOUT=512
    for (int k = tid; k < 1024; k += 256) {
      float v = (k < 512) ? Wl2[(size_t)k * 512 + n] : Wr2[(size_t)(k - 512) * 512 + n];
      t2[(size_t)n * 1024 + k] = f2fp8(v);
    }
  } else if (b < 1536) {
    int n = b - 1024;    // [Wl3|Wr3] along n: Kdim=512, half=256
    for (int k = tid; k < 512; k += 256) {
      float v = (n < 256) ? Wl3[(size_t)k * 256 + n] : Wr3[(size_t)k * 256 + (n - 256)];
      t3[(size_t)n * 512 + k] = f2fp8(v);
    }
  } else {
    int i = (b - 1536) * 256 + tid;
    if (i < NN * 128 / 8) {
      size_t o = (size_t)i * 8;
      float4 a = *(const float4*)(x + o);
      float4 c = *(const float4*)(x + o + 4);
      u32 p0 = f4fp8(a.x, a.y, a.z, a.w);
      u32 p1 = f4fp8(c.x, c.y, c.z, c.w);
      *(uint2*)(xf8 + o) = make_uint2(p0, p1);
    }
  }
}

// ---------------- aggregation (fp8 gather over CSR, fp8 out) ----------------
// R12-proven structure (x2 unroll, no NT hints).
__global__ void k_aggf512(const u8* __restrict__ xf8, const int* __restrict__ rowptr,
                          const int* __restrict__ csr_src, const float* __restrict__ csr_w,
                          u8* __restrict__ out) {
  int n = blockIdx.x;
  int t = threadIdx.x;  // 0..127
  int beg = rowptr[n], end = rowptr[n + 1];
  float4 acc = {0.f, 0.f, 0.f, 0.f};
  int e = beg;
  for (; e + 2 <= end; e += 2) {
    int s0 = csr_src[e], s1 = csr_src[e + 1];
    float w0 = csr_w[e], w1 = csr_w[e + 1];
    float4 v0 = fp8x4f(*(const u32*)(xf8 + (size_t)s0 * 512 + t * 4));
    float4 v1 = fp8x4f(*(const u32*)(xf8 + (size_t)s1 * 512 + t * 4));
    acc.x += v0.x * w0 + v1.x * w1;
    acc.y += v0.y * w0 + v1.y * w1;
    acc.z += v0.z * w0 + v1.z * w1;
    acc.w += v0.w * w0 + v1.w * w1;
  }
  if (e < end) {
    int s0 = csr_src[e];
    float w0 = csr_w[e];
    float4 v0 = fp8x4f(*(const u32*)(xf8 + (size_t)s0 * 512 + t * 4));
    acc.x += v0.x * w0; acc.y += v0.y * w0;
    acc.z += v0.z * w0; acc.w += v0.w * w0;
  }
  *(u32*)(out + (size_t)n * 512 + t * 4) = f4fp8(acc.x, acc.y, acc.z, acc.w);
}

__global__ void k_aggf128(const u8* __restrict__ xf8, const int* __restrict__ rowptr,
                          const int* __restrict__ csr_src, const float* __restrict__ csr_w,
                          u8* __restrict__ out) {
  int sub = threadIdx.x >> 5;
  int lane = threadIdx.x & 31;
  int n = blockIdx.x * 2 + sub;
  if (n >= NN) return;
  int beg = rowptr[n], end = rowptr[n + 1];
  float4 acc = {0.f, 0.f, 0.f, 0.f};
  int e = beg;
  for (; e + 2 <= end; e += 2) {
    int s0 = csr_src[e], s1 = csr_src[e + 1];
    float w0 = csr_w[e], w1 = csr_w[e + 1];
    float4 v0 = fp8x4f(*(const u32*)(xf8 + (size_t)s0 * 128 + lane * 4));
    float4 v1 = fp8x4f(*(const u32*)(xf8 + (size_t)s1 * 128 + lane * 4));
    acc.x += v0.x * w0 + v1.x * w1;
    acc.y += v0.y * w0 + v1.y * w1;
    acc.z += v0.z * w0 + v1.z * w1;
    acc.w += v0.w * w0 + v1.w * w1;
  }
  if (e < end) {
    int s0 = csr_src[e];
    float w0 = csr_w[e];
    float4 v0 = fp8x4f(*(const u32*)(xf8 + (size_t)s0 * 128 + lane * 4));
    acc.x += v0.x * w0; acc.y += v0.y * w0;
    acc.z += v0.z * w0; acc.w += v0.w * w0;
  }
  *(u32*)(out + (size_t)n * 128 + lane * 4) = f4fp8(acc.x, acc.y, acc.z, acc.w);
}

// L3 combine: h3 = relu(agg256(P) + Q + bl3); P,Q compact fp8 [N,256] planes
__global__ void k_aggcomb(const u8* __restrict__ P, const u8* __restrict__ Q,
                          const int* __restrict__ rowptr, const int* __restrict__ csr_src,
                          const float* __restrict__ csr_w,
                          const float* __restrict__ bl3, float* __restrict__ h3) {
  int sub = threadIdx.x >> 6;
  int lane = threadIdx.x & 63;
  int n = blockIdx.x * 2 + sub;
  if (n >= NN) return;
  int beg = rowptr[n], end = rowptr[n + 1];
  float4 acc = {0.f, 0.f, 0.f, 0.f};
  int e = beg;
  for (; e + 2 <= end; e += 2) {
    int s0 = csr_src[e], s1 = csr_src[e + 1];
    float w0 = csr_w[e], w1 = csr_w[e + 1];
    float4 v0 = fp8x4f(*(const u32*)(P + (size_t)s0 * 256 + lane * 4));
    float4 v1 = fp8x4f(*(const u32*)(P + (size_t)s1 * 256 + lane * 4));
    acc.x += v0.x * w0 + v1.x * w1;
    acc.y += v0.y * w0 + v1.y * w1;
    acc.z += v0.z * w0 + v1.z * w1;
    acc.w += v0.w * w0 + v1.w * w1;
  }
  if (e < end) {
    int s0 = csr_src[e];
    float w0 = csr_w[e];
    float4 v0 = fp8x4f(*(const u32*)(P + (size_t)s0 * 256 + lane * 4));
    acc.x += v0.x * w0; acc.y += v0.y * w0;
    acc.z += v0.z * w0; acc.w += v0.w * w0;
  }
  float4 qv = fp8x4f(*(const u32*)(Q + (size_t)n * 256 + lane * 4));
  float4 bb = *(const float4*)(bl3 + lane * 4);
  float4 o;
  o.x = fmaxf(acc.x + qv.x + bb.x, 0.f);
  o.y = fmaxf(acc.y + qv.y + bb.y, 0.f);
  o.z = fmaxf(acc.z + qv.z + bb.z, 0.f);
  o.w = fmaxf(acc.w + qv.w + bb.w, 0.f);
  *(float4*)(h3 + (size_t)n * 256 + lane * 4) = o;
}

// ------- fp8 MFMA GEMM: over A=[A0|A1], Wt[n][k] fp8; FOUT=512 -------
// EPI: 0 = relu(v+bias); 1 = relu(BN(v+bias)); 2 = raw v -> split compact
// P (cols<256) / Q (cols>=256) planes of stride 256.
template <int K, int W0, int EPI>
__global__ __launch_bounds__(256) void k_gemm(
    const u8* __restrict__ A0, const u8* __restrict__ A1,
    const u8* __restrict__ Wt, const float* __restrict__ bias,
    const float* __restrict__ gamma, const float* __restrict__ beta,
    const float* __restrict__ mean, const float* __restrict__ var,
    u8* __restrict__ O8g, u8* __restrict__ O8b) {
  constexpr int FOUT = 512;
  __shared__ char LDSC[32768];
  u8* AS = (u8*)LDSC;            // 16 KB A tile [128 rows][128 k fp8]
  u8* BS = (u8*)(LDSC + 16384);  // 16 KB B tile [128 cols][128 k fp8]
  int tid = threadIdx.x;
  int wid = tid >> 6, l = tid & 63;
  int wr = wid >> 1, wc = wid & 1;

  // bijective XCD swizzle + quad mapping
  int nwg = gridDim.x;  // 1564
  int q8 = nwg >> 3, r8 = nwg & 7;
  int xcd = blockIdx.x & 7, idx = blockIdx.x >> 3;
  int L = (xcd < r8 ? xcd * (q8 + 1) : r8 * (q8 + 1) + (xcd - r8) * q8) + idx;
  int n0 = (L >> 2) * 128, c0 = (L & 3) * 128;

  f32x4 acc[4][4] = {};

  int srw = 32 * wid + (l >> 3);  // staged row (+8j), 8 rows per instr
  int sch = l & 7;                // 16B chunk within 128B row

  for (int k0 = 0; k0 < K; k0 += 128) {
    __syncthreads();
    {
      const u8* s; int rs; int seg;
      if (k0 < W0) { s = A0; rs = W0; seg = k0; }
      else         { s = A1; rs = K - W0; seg = k0 - W0; }
#pragma unroll
      for (int j = 0; j < 4; ++j) {
        int r = srw + 8 * j;
        int gr = n0 + r;
        if (gr >= NN) gr = NN - 1;
        int cc = sch ^ (r & 7);
        gload_lds16(s + (size_t)gr * rs + seg + cc * 16, AS + (32 * wid + 8 * j) * 128);
      }
#pragma unroll
      for (int j = 0; j < 4; ++j) {
        int r = srw + 8 * j;
        int cc = sch ^ (r & 7);
        gload_lds16(Wt + (size_t)(c0 + r) * K + k0 + cc * 16, BS + (32 * wid + 8 * j) * 128);
      }
    }
    __syncthreads();

#pragma unroll
    for (int ks = 0; ks < 4; ++ks) {
      i64b b[4];
#pragma unroll
      for (int n = 0; n < 4; ++n) {
        int col = wc * 64 + n * 16 + (l & 15);
        int byte = (col * 128 + ks * 32 + ((l >> 4) << 3)) ^ ((col & 7) << 4);
        b[n] = *(const i64b*)((const char*)BS + byte);
      }
#pragma unroll
      for (int m = 0; m < 4; ++m) {
        int row = wr * 64 + m * 16 + (l & 15);
        int byte = (row * 128 + ks * 32 + ((l >> 4) << 3)) ^ ((row & 7) << 4);
        i64b a = *(const i64b*)((const char*)AS + byte);
#pragma unroll
        for (int n = 0; n < 4; ++n)
          acc[m][n] = __builtin_amdgcn_mfma_f32_16x16x32_fp8_fp8(a, b[n], acc[m][n], 0, 0, 0);
      }
    }
  }

  // ---- epilogue: EPI -> LDS restage (swizzled u8) -> coalesced 16B stores ----
  __syncthreads();
  u8* O8 = (u8*)LDSC;  // [128][128] u8 = 16 KB
#pragma unroll
  for (int n = 0; n < 4; ++n) {
    int colL = wc * 64 + n * 16 + (l & 15);
    int col = c0 + colL;
    float bs = (EPI == 2) ? 0.f : bias[col];
    float sc = 1.f, sf = 0.f;
    if (EPI == 1) {
      sc = rsqrtf(var[col] + BN_EPS) * gamma[col];
      sf = beta[col] - mean[col] * sc;
    }
#pragma unroll
    for (int m = 0; m < 4; ++m) {
      int rowL0 = wr * 64 + m * 16 + ((l >> 4) << 2);
#pragma unroll
      for (int r = 0; r < 4; ++r) {
        float v = acc[m][n][r];
        if (EPI != 2) {
          v += bs;
          if (EPI == 1) v = v * sc + sf;
          v = fmaxf(v, 0.f);
        }
        int rowL = rowL0 + r;
        int byte = (rowL * 128 + colL) ^ ((rowL & 7) << 4);
        O8[byte] = f2fp8(v);
      }
    }
  }
  __syncthreads();
#pragma unroll
  for (int i = 0; i < 4; ++i) {
    int chunk = i * 256 + tid;   // 0..1023 chunks of 16B
    int rowL = chunk >> 3;
    int cs = (chunk & 7) * 16;
    int rr = n0 + rowL;
    if (rr < NN) {
      int byte = (rowL * 128 + cs) ^ ((rowL & 7) << 4);
      uint4 val = *(const uint4*)((const char*)O8 + byte);
      if (EPI == 2) {
        // split compact planes, stride 256 (c0 is block-uniform)
        u8* dstp = (c0 < 256) ? O8g : O8b;
        int cc0 = (c0 < 256) ? c0 : c0 - 256;
        *(uint4*)(dstp + (size_t)rr * 256 + cc0 + cs) = val;
      } else {
        *(uint4*)(O8g + (size_t)rr * FOUT + c0 + cs) = val;
      }
    }
  }
}

// ---------------- pooling + MLP ----------------
__global__ void k_counts(const int* __restrict__ batch, float* __restrict__ cnt) {
  int g = threadIdx.x;  // 64 threads
  int lo = 0, hi = NN;
  while (lo < hi) { int m = (lo + hi) >> 1; if (batch[m] < g) lo = m + 1; else hi = m; }
  int a = lo;
  lo = 0; hi = NN;
  int g1 = g + 1;
  while (lo < hi) { int m = (lo + hi) >> 1; if (batch[m] < g1) lo = m + 1; else hi = m; }
  cnt[g] = (float)(lo - a);
}

__global__ void k_pool(const float* __restrict__ h, const int* __restrict__ batch,
                       float* __restrict__ sums) {
  int f = threadIdx.x;  // 256 features
  int n0 = blockIdx.x * 128;
  int n1 = n0 + 128; if (n1 > NN) n1 = NN;
  float acc = 0.f;
  int cur = clampi(batch[n0], 0, NG - 1);
  for (int n = n0; n < n1; ++n) {
    int g = clampi(batch[n], 0, NG - 1);
    if (g != cur) {
      atomicAdd(&sums[(size_t)cur * 256 + f], acc);
      acc = 0.f;
      cur = g;
    }
    acc += h[(size_t)n * 256 + f];
  }
  atomicAdd(&sums[(size_t)cur * 256 + f], acc);
}

__global__ void k_mlp(const float* __restrict__ sums, const float* __restrict__ cnt,
                      const float* __restrict__ W4, const float* __restrict__ b4,
                      const float* __restrict__ W5, const float* __restrict__ b5,
                      float* __restrict__ out) {
  __shared__ float g[256];
  int b = blockIdx.x, t = threadIdx.x;  // 64 threads
  float inv = 1.f / fmaxf(cnt[b], 1.f);
#pragma unroll
  for (int q = 0; q < 4; ++q) g[q * 64 + t] = sums[(size_t)b * 256 + q * 64 + t] * inv;
  __syncthreads();
  float acc = 0.f;
#pragma unroll 8
  for (int k = 0; k < 256; ++k) acc += g[k] * W4[k * 64 + t];
  float a = fmaxf(acc + b4[t], 0.f) * W5[t];
  for (int off = 32; off; off >>= 1) a += __shfl_down(a, off, 64);
  if (t == 0) out[b] = fmaxf(a + b5[0], 0.f);
}

// ---------------- launcher ----------------
extern "C" void kernel_launch(void* const* d_in, const int* in_sizes, int n_in,
                              void* d_out, int out_size, void* d_ws, size_t ws_size,
                              hipStream_t stream) {
  const float* x     = (const float*)d_in[0];
  const int*   eidx  = (const int*)d_in[1];
  const float* ew    = (const float*)d_in[2];
  const int*   batch = (const int*)d_in[3];
  const float* Wl1 = (const float*)d_in[4];
  const float* bl1 = (const float*)d_in[5];
  const float* Wr1 = (const float*)d_in[6];
  const float* Wl2 = (const float*)d_in[7];
  const float* bl2 = (const float*)d_in[8];
  const float* Wr2 = (const float*)d_in[9];
  const float* Wl3 = (const float*)d_in[10];
  const float* bl3 = (const float*)d_in[11];
  const float* Wr3 = (const float*)d_in[12];
  const float* gamma = (const float*)d_in[13];
  const float* beta  = (const float*)d_in[14];
  const float* mean  = (const float*)d_in[15];
  const float* var   = (const float*)d_in[16];
  const float* W4 = (const float*)d_in[17];
  const float* b4 = (const float*)d_in[18];
  const float* W5 = (const float*)d_in[19];
  const float* b5 = (const float*)d_in[20];

  const int* src = eidx;
  const int* dst = eidx + NE;

  // ---- workspace layout (~145 MB; ws_size known >= 313 MB) ----
  const size_t P8 = (size_t)NN * 512;      // 25.6 MB fp8 plane
  char* w = (char*)d_ws;
  u8*  X1f8 = (u8*)w; w += P8;             // h1 fp8
  u8*  X2f8 = (u8*)w; w += P8;             // h2 fp8
  u8*  Agf8 = (u8*)w; w += P8;             // agg stream; later P|Q compact planes
  u8*  Xf8  = (u8*)w; w += (size_t)NN * 128;
  float* h3 = (float*)w; w += (size_t)NN * 256 * 4;  // 51.2 MB fp32
  u8* Wt1 = (u8*)w; w += (size_t)512 * 256;
  u8* Wt2 = (u8*)w; w += (size_t)512 * 1024;
  u8* Wt3 = (u8*)w; w += (size_t)512 * 512;
  int*   csr_src = (int*)w;   w += (size_t)NE * 4;
  float* csr_w   = (float*)w; w += (size_t)NE * 4;
  int*   rowptr  = (int*)w;   w += ((size_t)NN + 4) * 4;
  int*   cursor  = (int*)w;   w += (size_t)NN * 4;
  int*   aux     = (int*)w;   w += 1024;
  float* sums    = (float*)w; w += (size_t)NG * 256 * 4;
  float* cnt     = (float*)w; w += 1024;
  u8* Pf8 = Agf8;                       // compact P [N,256]
  u8* Qf8 = Agf8 + (size_t)NN * 256;    // compact Q [N,256]

  int nblk = (NN + 255) / 256;  // 196

  // CSR build + fused prep (weights fp8 + x fp8)
  k_zero32<<<nblk, 256, 0, stream>>>((u32*)cursor, NN);
  k_count<<<(NE + 255) / 256, 256, 0, stream>>>(dst, cursor);
  k_scan_block<<<nblk, 256, 0, stream>>>(cursor, rowptr, aux);
  k_scan_aux<<<1, 256, 0, stream>>>(aux, nblk);
  k_fix<<<nblk, 256, 0, stream>>>(rowptr, aux, cursor);
  k_fill<<<(NE + 255) / 256, 256, 0, stream>>>(src, dst, ew, cursor, csr_src, csr_w);
  k_prep<<<1536 + (NN * 128 / 8 + 255) / 256, 256, 0, stream>>>(
      x, Xf8, Wl1, Wr1, Wt1, Wl2, Wr2, Wt2, Wl3, Wr3, Wt3);

  const int NWG = 391 * 4;  // 1564 (128x128 tiles over [50048 x 512])

  // Layer 1: agg(x fp8) -> Ag; h1 = relu([Ag|Xf8]@Wt1 + bl1) -> X1f8
  k_aggf128<<<(NN + 1) / 2, 64, 0, stream>>>(Xf8, rowptr, csr_src, csr_w, Agf8);
  k_gemm<256, 128, 0><<<NWG, 256, 0, stream>>>(
      Agf8, Xf8, Wt1, bl1, nullptr, nullptr, nullptr, nullptr, X1f8, nullptr);

  // Layer 2: agg(h1 fp8) -> Ag; h2 = relu(BN([Ag|h1]@Wt2 + bl2)) -> X2f8
  k_aggf512<<<NN, 128, 0, stream>>>(X1f8, rowptr, csr_src, csr_w, Agf8);
  k_gemm<1024, 512, 1><<<NWG, 256, 0, stream>>>(
      Agf8, X1f8, Wt2, bl2, gamma, beta, mean, var, X2f8, nullptr);

  // Layer 3: P = h2@Wl3, Q = h2@Wr3 (compact planes); h3 = relu(agg(P)+Q+bl3)
  k_gemm<512, 512, 2><<<NWG, 256, 0, stream>>>(
      X2f8, X2f8, Wt3, nullptr, nullptr, nullptr, nullptr, nullptr, Pf8, Qf8);
  k_aggcomb<<<(NN + 1) / 2, 128, 0, stream>>>(Pf8, Qf8, rowptr, csr_src, csr_w, bl3, h3);

  // pool + MLP
  k_zero32<<<(NG * 256 + 255) / 256, 256, 0, stream>>>((u32*)sums, NG * 256);
  k_pool<<<(NN + 127) / 128, 256, 0, stream>>>(h3, batch, sums);
  k_counts<<<1, 64, 0, stream>>>(batch, cnt);
  k_mlp<<<NG, 64, 0, stream>>>(sums, cnt, W4, b4, W5, b5, (float*)d_out);
}

// Round 16
// 401.629 us; speedup vs baseline: 1.2546x; 1.0652x over previous
//
#include <hip/hip_runtime.h>

#define NN 50000
#define NE 800000
#define NG 64
#define BN_EPS 1e-5f

typedef unsigned short u16;
typedef unsigned int u32;
typedef unsigned char u8;
typedef long i64b;
struct alignas(8) us4 { u16 x, y, z, w; };
typedef float f32x4 __attribute__((ext_vector_type(4)));

__device__ inline int clampi(int v, int lo, int hi) {
  return v < lo ? lo : (v > hi ? hi : v);
}
__device__ inline float bf2f(u16 h) { return __uint_as_float((u32)h << 16); }
__device__ inline u16 f2bf_rne(float f) {
  u32 u = __float_as_uint(f);
  return (u16)((u + 0x7fff + ((u >> 16) & 1)) >> 16);
}
// async global->LDS DMA, 16B per lane; LDS dest is wave-uniform base
__device__ inline void gload_lds16(const void* g, void* l) {
  __builtin_amdgcn_global_load_lds(
      (const __attribute__((address_space(1))) u32*)g,
      (__attribute__((address_space(3))) u32*)l, 16, 0, 0);
}
// fp8 e4m3 (OCP on gfx950) HW converts
__device__ inline float4 fp8x4f(u32 q) {
  float4 r;
  r.x = __builtin_amdgcn_cvt_f32_fp8(q, 0);
  r.y = __builtin_amdgcn_cvt_f32_fp8(q, 1);
  r.z = __builtin_amdgcn_cvt_f32_fp8(q, 2);
  r.w = __builtin_amdgcn_cvt_f32_fp8(q, 3);
  return r;
}
__device__ inline u32 f4fp8(float a, float b, float c, float d) {
  u32 p = __builtin_amdgcn_cvt_pk_fp8_f32(a, b, 0u, false);
  return __builtin_amdgcn_cvt_pk_fp8_f32(c, d, p, true);
}
__device__ inline u8 f2fp8(float v) {
  return (u8)(__builtin_amdgcn_cvt_pk_fp8_f32(v, 0.f, 0u, false) & 0xffu);
}

// ---------------- utility ----------------
__global__ void k_zero32(u32* __restrict__ p, int n) {
  int i = blockIdx.x * 256 + threadIdx.x;
  if (i < n) p[i] = 0u;
}

// ---------------- CSR build (proven) ----------------
__global__ void k_count(const int* __restrict__ dst, int* __restrict__ deg) {
  int e = blockIdx.x * 256 + threadIdx.x;
  if (e < NE) atomicAdd(&deg[clampi(dst[e], 0, NN - 1)], 1);
}

__global__ void k_scan_block(const int* __restrict__ deg, int* __restrict__ excl,
                             int* __restrict__ aux) {
  __shared__ int s[256];
  int t = threadIdx.x;
  int idx = blockIdx.x * 256 + t;
  int v = (idx < NN) ? deg[idx] : 0;
  s[t] = v;
  __syncthreads();
  for (int off = 1; off < 256; off <<= 1) {
    int x = (t >= off) ? s[t - off] : 0;
    __syncthreads();
    s[t] += x;
    __syncthreads();
  }
  if (idx < NN) excl[idx] = s[t] - v;
  if (t == 255) aux[blockIdx.x] = s[255];
}

__global__ void k_scan_aux(int* aux, int nblk) {
  __shared__ int s[256];
  int t = threadIdx.x;
  int v = (t < nblk) ? aux[t] : 0;
  s[t] = v;
  __syncthreads();
  for (int off = 1; off < 256; off <<= 1) {
    int x = (t >= off) ? s[t - off] : 0;
    __syncthreads();
    s[t] += x;
    __syncthreads();
  }
  if (t < nblk) aux[t] = s[t] - v;
}

__global__ void k_fix(int* __restrict__ rowptr, const int* __restrict__ aux,
                      int* __restrict__ cursor) {
  int idx = blockIdx.x * 256 + threadIdx.x;
  if (idx < NN) {
    int v = rowptr[idx] + aux[blockIdx.x];
    rowptr[idx] = v;
    cursor[idx] = v;
  }
  if (idx == 0) rowptr[NN] = NE;
}

__global__ void k_fill(const int* __restrict__ src, const int* __restrict__ dst,
                       const float* __restrict__ ew, int* __restrict__ cursor,
                       int* __restrict__ csr_src, float* __restrict__ csr_w) {
  int e = blockIdx.x * 256 + threadIdx.x;
  if (e < NE) {
    int d = clampi(dst[e], 0, NN - 1);
    int p = atomicAdd(&cursor[d], 1);
    p = clampi(p, 0, NE - 1);
    csr_src[p] = clampi(src[e], 0, NN - 1);
    csr_w[p] = ew[e];
  }
}

// ------- fused prep: weight transposes (fp8) + x -> fp8 conversion -------
__global__ void k_prep(const float* __restrict__ x, u8* __restrict__ xf8,
                       const float* __restrict__ Wl1, const float* __restrict__ Wr1,
                       u8* __restrict__ t1,
                       const float* __restrict__ Wl2, const float* __restrict__ Wr2,
                       u8* __restrict__ t2,
                       const float* __restrict__ Wl3, const float* __restrict__ Wr3,
                       u8* __restrict__ t3) {
  int b = blockIdx.x, tid = threadIdx.x;
  if (b < 512) {
    int n = b, k = tid;
    float v = (k < 128) ? Wl1[(size_t)k * 512 + n] : Wr1[(size_t)(k - 128) * 512 + n];
    t1[(size_t)n * 256 + k] = f2fp8(v);
  } else if (b < 1024) {
    int n = b - 512;
    for (int k = tid; k < 1024; k += 256) {
      float v = (k < 512) ? Wl2[(size_t)k * 512 + n] : Wr2[(size_t)(k - 512) * 512 + n];
      t2[(size_t)n * 1024 + k] = f2fp8(v);
    }
  } else if (b < 1536) {
    int n = b - 1024;
    for (int k = tid; k < 512; k += 256) {
      float v = (n < 256) ? Wl3[(size_t)k * 256 + n] : Wr3[(size_t)k * 256 + (n - 256)];
      t3[(size_t)n * 512 + k] = f2fp8(v);
    }
  } else {
    int i = (b - 1536) * 256 + tid;
    if (i < NN * 128 / 8) {
      size_t o = (size_t)i * 8;
      float4 a = *(const float4*)(x + o);
      float4 c = *(const float4*)(x + o + 4);
      u32 p0 = f4fp8(a.x, a.y, a.z, a.w);
      u32 p1 = f4fp8(c.x, c.y, c.z, c.w);
      *(uint2*)(xf8 + o) = make_uint2(p0, p1);
    }
  }
}

// ---------------- aggregation (fp8 gather over CSR, fp8 out) ----------------
// x4 edge unroll (no NT hints) for memory-level parallelism.
__global__ void k_aggf512(const u8* __restrict__ xf8, const int* __restrict__ rowptr,
                          const int* __restrict__ csr_src, const float* __restrict__ csr_w,
                          u8* __restrict__ out) {
  int n = blockIdx.x;
  int t = threadIdx.x;  // 0..127
  int beg = rowptr[n], end = rowptr[n + 1];
  float4 acc = {0.f, 0.f, 0.f, 0.f};
  int e = beg;
  for (; e + 4 <= end; e += 4) {
    int s0 = csr_src[e], s1 = csr_src[e + 1];
    int s2 = csr_src[e + 2], s3 = csr_src[e + 3];
    float w0 = csr_w[e], w1 = csr_w[e + 1];
    float w2 = csr_w[e + 2], w3 = csr_w[e + 3];
    u32 q0 = *(const u32*)(xf8 + (size_t)s0 * 512 + t * 4);
    u32 q1 = *(const u32*)(xf8 + (size_t)s1 * 512 + t * 4);
    u32 q2 = *(const u32*)(xf8 + (size_t)s2 * 512 + t * 4);
    u32 q3 = *(const u32*)(xf8 + (size_t)s3 * 512 + t * 4);
    float4 v0 = fp8x4f(q0), v1 = fp8x4f(q1), v2 = fp8x4f(q2), v3 = fp8x4f(q3);
    acc.x += v0.x * w0 + v1.x * w1 + v2.x * w2 + v3.x * w3;
    acc.y += v0.y * w0 + v1.y * w1 + v2.y * w2 + v3.y * w3;
    acc.z += v0.z * w0 + v1.z * w1 + v2.z * w2 + v3.z * w3;
    acc.w += v0.w * w0 + v1.w * w1 + v2.w * w2 + v3.w * w3;
  }
  for (; e < end; ++e) {
    int s0 = csr_src[e];
    float w0 = csr_w[e];
    float4 v0 = fp8x4f(*(const u32*)(xf8 + (size_t)s0 * 512 + t * 4));
    acc.x += v0.x * w0; acc.y += v0.y * w0;
    acc.z += v0.z * w0; acc.w += v0.w * w0;
  }
  *(u32*)(out + (size_t)n * 512 + t * 4) = f4fp8(acc.x, acc.y, acc.z, acc.w);
}

__global__ void k_aggf128(const u8* __restrict__ xf8, const int* __restrict__ rowptr,
                          const int* __restrict__ csr_src, const float* __restrict__ csr_w,
                          u8* __restrict__ out) {
  int sub = threadIdx.x >> 5;
  int lane = threadIdx.x & 31;
  int n = blockIdx.x * 2 + sub;
  if (n >= NN) return;
  int beg = rowptr[n], end = rowptr[n + 1];
  float4 acc = {0.f, 0.f, 0.f, 0.f};
  int e = beg;
  for (; e + 2 <= end; e += 2) {
    int s0 = csr_src[e], s1 = csr_src[e + 1];
    float w0 = csr_w[e], w1 = csr_w[e + 1];
    float4 v0 = fp8x4f(*(const u32*)(xf8 + (size_t)s0 * 128 + lane * 4));
    float4 v1 = fp8x4f(*(const u32*)(xf8 + (size_t)s1 * 128 + lane * 4));
    acc.x += v0.x * w0 + v1.x * w1;
    acc.y += v0.y * w0 + v1.y * w1;
    acc.z += v0.z * w0 + v1.z * w1;
    acc.w += v0.w * w0 + v1.w * w1;
  }
  if (e < end) {
    int s0 = csr_src[e];
    float w0 = csr_w[e];
    float4 v0 = fp8x4f(*(const u32*)(xf8 + (size_t)s0 * 128 + lane * 4));
    acc.x += v0.x * w0; acc.y += v0.y * w0;
    acc.z += v0.z * w0; acc.w += v0.w * w0;
  }
  *(u32*)(out + (size_t)n * 128 + lane * 4) = f4fp8(acc.x, acc.y, acc.z, acc.w);
}

// L3 combine: h3 = relu(agg256(P) + Q + bl3) -> bf16; P,Q compact fp8 [N,256]
__global__ void k_aggcomb(const u8* __restrict__ P, const u8* __restrict__ Q,
                          const int* __restrict__ rowptr, const int* __restrict__ csr_src,
                          const float* __restrict__ csr_w,
                          const float* __restrict__ bl3, u16* __restrict__ h3) {
  int sub = threadIdx.x >> 6;
  int lane = threadIdx.x & 63;
  int n = blockIdx.x * 2 + sub;
  if (n >= NN) return;
  int beg = rowptr[n], end = rowptr[n + 1];
  float4 acc = {0.f, 0.f, 0.f, 0.f};
  int e = beg;
  for (; e + 4 <= end; e += 4) {
    int s0 = csr_src[e], s1 = csr_src[e + 1];
    int s2 = csr_src[e + 2], s3 = csr_src[e + 3];
    float w0 = csr_w[e], w1 = csr_w[e + 1];
    float w2 = csr_w[e + 2], w3 = csr_w[e + 3];
    float4 v0 = fp8x4f(*(const u32*)(P + (size_t)s0 * 256 + lane * 4));
    float4 v1 = fp8x4f(*(const u32*)(P + (size_t)s1 * 256 + lane * 4));
    float4 v2 = fp8x4f(*(const u32*)(P + (size_t)s2 * 256 + lane * 4));
    float4 v3 = fp8x4f(*(const u32*)(P + (size_t)s3 * 256 + lane * 4));
    acc.x += v0.x * w0 + v1.x * w1 + v2.x * w2 + v3.x * w3;
    acc.y += v0.y * w0 + v1.y * w1 + v2.y * w2 + v3.y * w3;
    acc.z += v0.z * w0 + v1.z * w1 + v2.z * w2 + v3.z * w3;
    acc.w += v0.w * w0 + v1.w * w1 + v2.w * w2 + v3.w * w3;
  }
  for (; e < end; ++e) {
    int s0 = csr_src[e];
    float w0 = csr_w[e];
    float4 v0 = fp8x4f(*(const u32*)(P + (size_t)s0 * 256 + lane * 4));
    acc.x += v0.x * w0; acc.y += v0.y * w0;
    acc.z += v0.z * w0; acc.w += v0.w * w0;
  }
  float4 qv = fp8x4f(*(const u32*)(Q + (size_t)n * 256 + lane * 4));
  float4 bb = *(const float4*)(bl3 + lane * 4);
  us4 o;
  o.x = f2bf_rne(fmaxf(acc.x + qv.x + bb.x, 0.f));
  o.y = f2bf_rne(fmaxf(acc.y + qv.y + bb.y, 0.f));
  o.z = f2bf_rne(fmaxf(acc.z + qv.z + bb.z, 0.f));
  o.w = f2bf_rne(fmaxf(acc.w + qv.w + bb.w, 0.f));
  *(us4*)(h3 + (size_t)n * 256 + lane * 4) = o;
}

// ------- fp8 MFMA GEMM: over A=[A0|A1], Wt[n][k] fp8; FOUT=512 -------
// EPI: 0 = relu(v+bias); 1 = relu(BN(v+bias)); 2 = raw v -> split compact
// P (cols<256) / Q (cols>=256) planes of stride 256.
template <int K, int W0, int EPI>
__global__ __launch_bounds__(256) void k_gemm(
    const u8* __restrict__ A0, const u8* __restrict__ A1,
    const u8* __restrict__ Wt, const float* __restrict__ bias,
    const float* __restrict__ gamma, const float* __restrict__ beta,
    const float* __restrict__ mean, const float* __restrict__ var,
    u8* __restrict__ O8g, u8* __restrict__ O8b) {
  constexpr int FOUT = 512;
  __shared__ char LDSC[32768];
  u8* AS = (u8*)LDSC;            // 16 KB A tile [128 rows][128 k fp8]
  u8* BS = (u8*)(LDSC + 16384);  // 16 KB B tile [128 cols][128 k fp8]
  int tid = threadIdx.x;
  int wid = tid >> 6, l = tid & 63;
  int wr = wid >> 1, wc = wid & 1;

  // bijective XCD swizzle + quad mapping
  int nwg = gridDim.x;  // 1564
  int q8 = nwg >> 3, r8 = nwg & 7;
  int xcd = blockIdx.x & 7, idx = blockIdx.x >> 3;
  int L = (xcd < r8 ? xcd * (q8 + 1) : r8 * (q8 + 1) + (xcd - r8) * q8) + idx;
  int n0 = (L >> 2) * 128, c0 = (L & 3) * 128;

  f32x4 acc[4][4] = {};

  int srw = 32 * wid + (l >> 3);  // staged row (+8j), 8 rows per instr
  int sch = l & 7;                // 16B chunk within 128B row

  for (int k0 = 0; k0 < K; k0 += 128) {
    __syncthreads();
    {
      const u8* s; int rs; int seg;
      if (k0 < W0) { s = A0; rs = W0; seg = k0; }
      else         { s = A1; rs = K - W0; seg = k0 - W0; }
#pragma unroll
      for (int j = 0; j < 4; ++j) {
        int r = srw + 8 * j;
        int gr = n0 + r;
        if (gr >= NN) gr = NN - 1;
        int cc = sch ^ (r & 7);
        gload_lds16(s + (size_t)gr * rs + seg + cc * 16, AS + (32 * wid + 8 * j) * 128);
      }
#pragma unroll
      for (int j = 0; j < 4; ++j) {
        int r = srw + 8 * j;
        int cc = sch ^ (r & 7);
        gload_lds16(Wt + (size_t)(c0 + r) * K + k0 + cc * 16, BS + (32 * wid + 8 * j) * 128);
      }
    }
    __syncthreads();

#pragma unroll
    for (int ks = 0; ks < 4; ++ks) {
      i64b b[4];
#pragma unroll
      for (int n = 0; n < 4; ++n) {
        int col = wc * 64 + n * 16 + (l & 15);
        int byte = (col * 128 + ks * 32 + ((l >> 4) << 3)) ^ ((col & 7) << 4);
        b[n] = *(const i64b*)((const char*)BS + byte);
      }
#pragma unroll
      for (int m = 0; m < 4; ++m) {
        int row = wr * 64 + m * 16 + (l & 15);
        int byte = (row * 128 + ks * 32 + ((l >> 4) << 3)) ^ ((row & 7) << 4);
        i64b a = *(const i64b*)((const char*)AS + byte);
#pragma unroll
        for (int n = 0; n < 4; ++n)
          acc[m][n] = __builtin_amdgcn_mfma_f32_16x16x32_fp8_fp8(a, b[n], acc[m][n], 0, 0, 0);
      }
    }
  }

  // ---- epilogue: EPI -> LDS restage (swizzled u8) -> coalesced 16B stores ----
  __syncthreads();
  u8* O8 = (u8*)LDSC;  // [128][128] u8 = 16 KB
#pragma unroll
  for (int n = 0; n < 4; ++n) {
    int colL = wc * 64 + n * 16 + (l & 15);
    int col = c0 + colL;
    float bs = (EPI == 2) ? 0.f : bias[col];
    float sc = 1.f, sf = 0.f;
    if (EPI == 1) {
      sc = rsqrtf(var[col] + BN_EPS) * gamma[col];
      sf = beta[col] - mean[col] * sc;
    }
#pragma unroll
    for (int m = 0; m < 4; ++m) {
      int rowL0 = wr * 64 + m * 16 + ((l >> 4) << 2);
#pragma unroll
      for (int r = 0; r < 4; ++r) {
        float v = acc[m][n][r];
        if (EPI != 2) {
          v += bs;
          if (EPI == 1) v = v * sc + sf;
          v = fmaxf(v, 0.f);
        }
        int rowL = rowL0 + r;
        int byte = (rowL * 128 + colL) ^ ((rowL & 7) << 4);
        O8[byte] = f2fp8(v);
      }
    }
  }
  __syncthreads();
#pragma unroll
  for (int i = 0; i < 4; ++i) {
    int chunk = i * 256 + tid;   // 0..1023 chunks of 16B
    int rowL = chunk >> 3;
    int cs = (chunk & 7) * 16;
    int rr = n0 + rowL;
    if (rr < NN) {
      int byte = (rowL * 128 + cs) ^ ((rowL & 7) << 4);
      uint4 val = *(const uint4*)((const char*)O8 + byte);
      if (EPI == 2) {
        u8* dstp = (c0 < 256) ? O8g : O8b;
        int cc0 = (c0 < 256) ? c0 : c0 - 256;
        *(uint4*)(dstp + (size_t)rr * 256 + cc0 + cs) = val;
      } else {
        *(uint4*)(O8g + (size_t)rr * FOUT + c0 + cs) = val;
      }
    }
  }
}

// ---------------- pooling + MLP ----------------
__global__ void k_counts(const int* __restrict__ batch, float* __restrict__ cnt) {
  int g = threadIdx.x;  // 64 threads
  int lo = 0, hi = NN;
  while (lo < hi) { int m = (lo + hi) >> 1; if (batch[m] < g) lo = m + 1; else hi = m; }
  int a = lo;
  lo = 0; hi = NN;
  int g1 = g + 1;
  while (lo < hi) { int m = (lo + hi) >> 1; if (batch[m] < g1) lo = m + 1; else hi = m; }
  cnt[g] = (float)(lo - a);
}

__global__ void k_pool(const u16* __restrict__ h, const int* __restrict__ batch,
                       float* __restrict__ sums) {
  int f = threadIdx.x;  // 256 features
  int n0 = blockIdx.x * 128;
  int n1 = n0 + 128; if (n1 > NN) n1 = NN;
  float acc = 0.f;
  int cur = clampi(batch[n0], 0, NG - 1);
  for (int n = n0; n < n1; ++n) {
    int g = clampi(batch[n], 0, NG - 1);
    if (g != cur) {
      atomicAdd(&sums[(size_t)cur * 256 + f], acc);
      acc = 0.f;
      cur = g;
    }
    acc += bf2f(h[(size_t)n * 256 + f]);
  }
  atomicAdd(&sums[(size_t)cur * 256 + f], acc);
}

__global__ void k_mlp(const float* __restrict__ sums, const float* __restrict__ cnt,
                      const float* __restrict__ W4, const float* __restrict__ b4,
                      const float* __restrict__ W5, const float* __restrict__ b5,
                      float* __restrict__ out) {
  __shared__ float g[256];
  int b = blockIdx.x, t = threadIdx.x;  // 64 threads
  float inv = 1.f / fmaxf(cnt[b], 1.f);
#pragma unroll
  for (int q = 0; q < 4; ++q) g[q * 64 + t] = sums[(size_t)b * 256 + q * 64 + t] * inv;
  __syncthreads();
  float acc = 0.f;
#pragma unroll 8
  for (int k = 0; k < 256; ++k) acc += g[k] * W4[k * 64 + t];
  float a = fmaxf(acc + b4[t], 0.f) * W5[t];
  for (int off = 32; off; off >>= 1) a += __shfl_down(a, off, 64);
  if (t == 0) out[b] = fmaxf(a + b5[0], 0.f);
}

// ---------------- launcher ----------------
extern "C" void kernel_launch(void* const* d_in, const int* in_sizes, int n_in,
                              void* d_out, int out_size, void* d_ws, size_t ws_size,
                              hipStream_t stream) {
  const float* x     = (const float*)d_in[0];
  const int*   eidx  = (const int*)d_in[1];
  const float* ew    = (const float*)d_in[2];
  const int*   batch = (const int*)d_in[3];
  const float* Wl1 = (const float*)d_in[4];
  const float* bl1 = (const float*)d_in[5];
  const float* Wr1 = (const float*)d_in[6];
  const float* Wl2 = (const float*)d_in[7];
  const float* bl2 = (const float*)d_in[8];
  const float* Wr2 = (const float*)d_in[9];
  const float* Wl3 = (const float*)d_in[10];
  const float* bl3 = (const float*)d_in[11];
  const float* Wr3 = (const float*)d_in[12];
  const float* gamma = (const float*)d_in[13];
  const float* beta  = (const float*)d_in[14];
  const float* mean  = (const float*)d_in[15];
  const float* var   = (const float*)d_in[16];
  const float* W4 = (const float*)d_in[17];
  const float* b4 = (const float*)d_in[18];
  const float* W5 = (const float*)d_in[19];
  const float* b5 = (const float*)d_in[20];

  const int* src = eidx;
  const int* dst = eidx + NE;

  // ---- workspace layout (~120 MB; ws_size known >= 313 MB) ----
  const size_t P8 = (size_t)NN * 512;      // 25.6 MB fp8 plane
  char* w = (char*)d_ws;
  u8*  X1f8 = (u8*)w; w += P8;             // h1 fp8
  u8*  X2f8 = (u8*)w; w += P8;             // h2 fp8
  u8*  Agf8 = (u8*)w; w += P8;             // agg stream; later P|Q compact planes
  u8*  Xf8  = (u8*)w; w += (size_t)NN * 128;
  u16* h3 = (u16*)w; w += (size_t)NN * 256 * 2;  // 25.6 MB bf16
  u8* Wt1 = (u8*)w; w += (size_t)512 * 256;
  u8* Wt2 = (u8*)w; w += (size_t)512 * 1024;
  u8* Wt3 = (u8*)w; w += (size_t)512 * 512;
  int*   csr_src = (int*)w;   w += (size_t)NE * 4;
  float* csr_w   = (float*)w; w += (size_t)NE * 4;
  int*   rowptr  = (int*)w;   w += ((size_t)NN + 4) * 4;
  int*   cursor  = (int*)w;   w += (size_t)NN * 4;
  int*   aux     = (int*)w;   w += 1024;
  float* sums    = (float*)w; w += (size_t)NG * 256 * 4;
  float* cnt     = (float*)w; w += 1024;
  u8* Pf8 = Agf8;                       // compact P [N,256]
  u8* Qf8 = Agf8 + (size_t)NN * 256;    // compact Q [N,256]

  int nblk = (NN + 255) / 256;  // 196

  // CSR build + fused prep (weights fp8 + x fp8)
  k_zero32<<<nblk, 256, 0, stream>>>((u32*)cursor, NN);
  k_count<<<(NE + 255) / 256, 256, 0, stream>>>(dst, cursor);
  k_scan_block<<<nblk, 256, 0, stream>>>(cursor, rowptr, aux);
  k_scan_aux<<<1, 256, 0, stream>>>(aux, nblk);
  k_fix<<<nblk, 256, 0, stream>>>(rowptr, aux, cursor);
  k_fill<<<(NE + 255) / 256, 256, 0, stream>>>(src, dst, ew, cursor, csr_src, csr_w);
  k_prep<<<1536 + (NN * 128 / 8 + 255) / 256, 256, 0, stream>>>(
      x, Xf8, Wl1, Wr1, Wt1, Wl2, Wr2, Wt2, Wl3, Wr3, Wt3);

  const int NWG = 391 * 4;  // 1564 (128x128 tiles over [50048 x 512])

  // Layer 1: agg(x fp8) -> Ag; h1 = relu([Ag|Xf8]@Wt1 + bl1) -> X1f8
  k_aggf128<<<(NN + 1) / 2, 64, 0, stream>>>(Xf8, rowptr, csr_src, csr_w, Agf8);
  k_gemm<256, 128, 0><<<NWG, 256, 0, stream>>>(
      Agf8, Xf8, Wt1, bl1, nullptr, nullptr, nullptr, nullptr, X1f8, nullptr);

  // Layer 2: agg(h1 fp8) -> Ag; h2 = relu(BN([Ag|h1]@Wt2 + bl2)) -> X2f8
  k_aggf512<<<NN, 128, 0, stream>>>(X1f8, rowptr, csr_src, csr_w, Agf8);
  k_gemm<1024, 512, 1><<<NWG, 256, 0, stream>>>(
      Agf8, X1f8, Wt2, bl2, gamma, beta, mean, var, X2f8, nullptr);

  // Layer 3: P = h2@Wl3, Q = h2@Wr3 (compact planes); h3 = relu(agg(P)+Q+bl3)
  k_gemm<512, 512, 2><<<NWG, 256, 0, stream>>>(
      X2f8, X2f8, Wt3, nullptr, nullptr, nullptr, nullptr, nullptr, Pf8, Qf8);
  k_aggcomb<<<(NN + 1) / 2, 128, 0, stream>>>(Pf8, Qf8, rowptr, csr_src, csr_w, bl3, h3);

  // pool + MLP
  k_zero32<<<(NG * 256 + 255) / 256, 256, 0, stream>>>((u32*)sums, NG * 256);
  k_pool<<<(NN + 127) / 128, 256, 0, stream>>>(h3, batch, sums);
  k_counts<<<1, 64, 0, stream>>>(batch, cnt);
  k_mlp<<<NG, 64, 0, stream>>>(sums, cnt, W4, b4, W5, b5, (float*)d_out);
}